// Round 17
// baseline (365.284 us; speedup 1.0000x reference)
//
#include <hip/hip_runtime.h>
#include <hip/hip_fp16.h>
#include <math.h>

#define B_   2
#define C_   256
#define T_   32
#define HW_  1024
#define THW_ 32768

using u32 = unsigned int;
typedef __attribute__((ext_vector_type(8))) short bf8_t;   // 8 bf16 in 4 VGPRs
typedef __attribute__((ext_vector_type(8))) unsigned short us8_t;
typedef __attribute__((ext_vector_type(8))) _Float16 h8_t; // 8 f16 in 4 VGPRs
typedef __attribute__((ext_vector_type(2))) __fp16 fp16v2; // builtin cvt_pkrtz return type
typedef __attribute__((ext_vector_type(4))) float f4_t;

static __device__ __forceinline__ unsigned short f2bf(float x){
  u32 u = __float_as_uint(x);
  u32 r = (u + 0x7FFF + ((u >> 16) & 1)) >> 16;   // RNE
  return (unsigned short)r;
}
static __device__ __forceinline__ float h2f_u(unsigned short u){
  union { __half h; unsigned short us; } cv; cv.us = u; return __half2float(cv.h);
}
static __device__ __forceinline__ unsigned short f2h_u(float f){
  union { __half h; unsigned short us; } cv; cv.h = __float2half(f); return cv.us;
}
static __device__ __forceinline__ u32 pkrtz(float a, float b){
  union { fp16v2 h; u32 w; } cv; cv.h = __builtin_amdgcn_cvt_pkrtz(a, b); return cv.w;
}
static __device__ __forceinline__ float ldf(const float* p){ return *p; }
static __device__ __forceinline__ float ldf(const __half* p){ return __half2float(*p); }

// ---------------- rope table ----------------
__global__ void k_rope_table(float* __restrict__ cosT, float* __restrict__ sinT){
  int tid = threadIdx.x;            // 512 threads, tid = i*16+u
  int i = tid >> 4, u = tid & 15;
  float invf = powf(10000.f, -(2.f * (float)u) / 32.f);
  float s, c;
  sincosf((float)i * invf, &s, &c);
  cosT[tid] = c;
  sinT[tid] = s;
}

// ---------------- weight cvt: stack w_qkv(768), gate_w(768), proj_w(256) as bf16 [1792][256] --
__global__ void k_wcvt(const float* __restrict__ w_qkv, const float* __restrict__ gate_w,
                       const float* __restrict__ proj_w, unsigned short* __restrict__ out){
  int row = blockIdx.x, c = threadIdx.x;
  const float* src = (row < 768) ? w_qkv + (size_t)row * 256
                   : (row < 1536) ? gate_w + (size_t)(row - 768) * 256
                                  : proj_w + (size_t)(row - 1536) * 256;
  out[(size_t)row * 256 + c] = f2bf(src[c]);
}

// ---------------- transpose+cvt: [b][256][THW] f32 -> bf16 [b][THW][256] ----------------
template<typename InT>
__global__ __launch_bounds__(256) void k_transpose_cvt(
    const InT* __restrict__ in, unsigned short* __restrict__ outT)
{
  __shared__ float tile[64][65];
  int s0 = blockIdx.x * 64;     // 512
  int c0 = blockIdx.y * 64;     // 4
  int b  = blockIdx.z;
  int tid = threadIdx.x;
  for (int idx = tid; idx < 4096; idx += 256){
    int c = idx >> 6, s = idx & 63;
    tile[c][s] = ldf(&in[((size_t)(b * C_ + c0 + c)) * THW_ + s0 + s]);
  }
  __syncthreads();
  for (int idx = tid; idx < 4096; idx += 256){
    int s = idx >> 6, c = idx & 63;
    outT[((size_t)b * THW_ + s0 + s) * 256 + c0 + c] = f2bf(tile[c][s]);
  }
}

// ---------------- MFMA GEMM core (bf16 A bank): 128xBN tile, K=256 ----------------
template<int BN>
static __device__ __forceinline__ void gemm_core_b(
    const unsigned short* __restrict__ A, int o0,
    const unsigned short* __restrict__ BT,   // pre-offset: + (b*THW + s0)*256
    unsigned short* As, unsigned short* Bs, f4_t acc[4][BN / 32])
{
  const int tid = threadIdx.x;
  const int lane = tid & 63, wv = tid >> 6;
  const int wm = wv >> 1, wn = wv & 1;
  const int m = lane & 15, kg = lane >> 4;
  const int arow = tid >> 1, aseg = (tid & 1) * 64;     // A: 128 rows, 2 thr/row, 64B each
  const int brow = (BN == 128) ? (tid >> 1) : (tid >> 2);
  const int bseg = (BN == 128) ? (tid & 1) * 64 : (tid & 3) * 32;
  for (int ks = 0; ks < 4; ks++){
    __syncthreads();                                    // protect prior reads
    {
      const unsigned short* ga = A + (size_t)(o0 + arow) * 256 + ks * 64 + aseg / 2;
      #pragma unroll
      for (int q2 = 0; q2 < 4; q2++){
        us8_t v = *(const us8_t*)(ga + q2 * 8);
        *(us8_t*)((char*)As + arow * 128 + ((aseg + q2 * 16) ^ ((arow & 7) << 4))) = v;
      }
      const unsigned short* gb = BT + (size_t)brow * 256 + ks * 64 + bseg / 2;
      #pragma unroll
      for (int q2 = 0; q2 < (BN == 128 ? 4 : 2); q2++){
        us8_t v = *(const us8_t*)(gb + q2 * 8);
        *(us8_t*)((char*)Bs + brow * 128 + ((bseg + q2 * 16) ^ ((brow & 7) << 4))) = v;
      }
    }
    __syncthreads();
    #pragma unroll
    for (int kk = 0; kk < 2; kk++){
      bf8_t af[4], bfr[BN / 32];
      #pragma unroll
      for (int mi = 0; mi < 4; mi++){
        int row = wm * 64 + mi * 16 + m;
        af[mi] = *(const bf8_t*)((const char*)As + row * 128 + ((kk * 64 + kg * 16) ^ ((row & 7) << 4)));
      }
      #pragma unroll
      for (int ni = 0; ni < BN / 32; ni++){
        int row = wn * (BN / 2) + ni * 16 + m;
        bfr[ni] = *(const bf8_t*)((const char*)Bs + row * 128 + ((kk * 64 + kg * 16) ^ ((row & 7) << 4)));
      }
      #pragma unroll
      for (int mi = 0; mi < 4; mi++)
        #pragma unroll
        for (int ni = 0; ni < BN / 32; ni++)
          acc[mi][ni] = __builtin_amdgcn_mfma_f32_16x16x32_bf16(af[mi], bfr[ni], acc[mi][ni], 0, 0, 0);
    }
  }
}

// ---------------- qkv GEMM: Wq(bf16)[768][256] @ x -> q,k,v (f16); XCD-swizzled 1D grid ------
__global__ __launch_bounds__(256) void k_mfma_qkv(
    const unsigned short* __restrict__ Wb, const unsigned short* __restrict__ xT,
    __half* __restrict__ q, __half* __restrict__ k, __half* __restrict__ v)
{
  __shared__ unsigned short As[8192], Bs[8192];
  int swz = (blockIdx.x & 7) * 384 + (blockIdx.x >> 3);   // 3072 blocks, %8==0
  const int bo = swz % 6;  swz /= 6;
  const int s0 = (swz & 255) * 128;
  const int b  = swz >> 8;
  f4_t acc[4][4];
  #pragma unroll
  for (int mi = 0; mi < 4; mi++)
    #pragma unroll
    for (int ni = 0; ni < 4; ni++) acc[mi][ni] = (f4_t)0.f;
  gemm_core_b<128>(Wb, bo * 128, xT + ((size_t)b * THW_ + s0) * 256, As, Bs, acc);
  __half* outp = (bo < 2) ? q : (bo < 4) ? k : v;
  const int ro = (bo & 1) * 128;
  const int lane = threadIdx.x & 63, wv = threadIdx.x >> 6;
  const int wm = wv >> 1, wn = wv & 1;
  size_t obase = (size_t)(b * C_) * THW_;
  #pragma unroll
  for (int mi = 0; mi < 4; mi++)
    #pragma unroll
    for (int ni = 0; ni < 4; ni++)
      #pragma unroll
      for (int r = 0; r < 4; r++){
        int o = ro + wm * 64 + mi * 16 + (lane >> 4) * 4 + r;
        int s = s0 + wn * 64 + ni * 16 + (lane & 15);
        outp[obase + (size_t)o * THW_ + s] = __float2half(acc[mi][ni][r]);
      }
}

// ---------------- gate GEMM + sigmoid + combine, 3 slices, yT direct; LDS-staged ctx --------
__global__ __launch_bounds__(256) void k_mfma_gate2(
    const unsigned short* __restrict__ Wb,   // bf16 gate bank [768][256]
    const unsigned short* __restrict__ xT,
    const float* __restrict__ gb,
    const __half* __restrict__ ctx_t, const __half* __restrict__ ctx_h,
    const __half* __restrict__ ctx_w,
    unsigned short* __restrict__ yT)         // bf16 [b][THW][256]
{
  __shared__ unsigned short As3[13056];      // main loop: 3x4096 W tiles; epilogue: 3x[64][68] ctx
  __shared__ unsigned short Bs[4096];
  int swz = (blockIdx.x & 7) * 512 + (blockIdx.x >> 3);   // 4096 blocks
  const int bo = swz & 3;  swz >>= 2;
  const int s0 = (swz & 511) * 64;
  const int b  = swz >> 9;
  const int tid = threadIdx.x;
  const int lane = tid & 63, wv = tid >> 6;
  const int wm = wv >> 1, wn = wv & 1;
  const int m = lane & 15, kg = lane >> 4;
  const unsigned short* xbase = xT + ((size_t)b * THW_ + s0) * 256;
  const size_t obase = (size_t)(b * C_) * THW_;

  f4_t acc[3][2][2];
  #pragma unroll
  for (int sl = 0; sl < 3; sl++)
    #pragma unroll
    for (int mi = 0; mi < 2; mi++)
      #pragma unroll
      for (int ni = 0; ni < 2; ni++) acc[sl][mi][ni] = (f4_t)0.f;

  for (int ks = 0; ks < 4; ks++){
    __syncthreads();
    #pragma unroll
    for (int rep = 0; rep < 2; rep++){
      int idx = rep * 256 + tid;              // 0..511
      int row = idx >> 3, seg = idx & 7;
      us8_t v = *(const us8_t*)(xbase + (size_t)row * 256 + ks * 64 + seg * 8);
      *(us8_t*)((char*)Bs + row * 128 + ((seg * 16) ^ ((row & 7) << 4))) = v;
    }
    #pragma unroll
    for (int sl = 0; sl < 3; sl++){
      #pragma unroll
      for (int rep = 0; rep < 2; rep++){
        int idx = rep * 256 + tid;
        int row = idx >> 3, seg = idx & 7;
        us8_t v = *(const us8_t*)(Wb + (size_t)(sl * 256 + bo * 64 + row) * 256 + ks * 64 + seg * 8);
        *(us8_t*)((char*)As3 + sl * 8192 + row * 128 + ((seg * 16) ^ ((row & 7) << 4))) = v;
      }
    }
    __syncthreads();
    #pragma unroll
    for (int kk = 0; kk < 2; kk++){
      bf8_t bfr[2], af[3][2];
      #pragma unroll
      for (int ni = 0; ni < 2; ni++){
        int row = wn * 32 + ni * 16 + m;
        bfr[ni] = *(const bf8_t*)((const char*)Bs + row * 128 + ((kk * 64 + kg * 16) ^ ((row & 7) << 4)));
      }
      #pragma unroll
      for (int sl = 0; sl < 3; sl++)
        #pragma unroll
        for (int mi = 0; mi < 2; mi++){
          int row = wm * 32 + mi * 16 + m;
          af[sl][mi] = *(const bf8_t*)((const char*)As3 + sl * 8192 + row * 128 + ((kk * 64 + kg * 16) ^ ((row & 7) << 4)));
        }
      #pragma unroll
      for (int sl = 0; sl < 3; sl++)
        #pragma unroll
        for (int mi = 0; mi < 2; mi++)
          #pragma unroll
          for (int ni = 0; ni < 2; ni++)
            acc[sl][mi][ni] = __builtin_amdgcn_mfma_f32_16x16x32_bf16(af[sl][mi], bfr[ni], acc[sl][mi][ni], 0, 0, 0);
    }
  }

  // ---- stage ctx tiles into LDS: 3 slices x [64 o][68 stride] f16, us8 global loads ----
  __syncthreads();                            // MFMA reads of As3 done
  #pragma unroll
  for (int rep = 0; rep < 6; rep++){
    int job = rep * 256 + tid;                // 0..1535 = sl(3) x row(64) x c8(8)
    int sl = job >> 9;
    int row = (job >> 3) & 63;
    int c8 = job & 7;
    const __half* cp = (sl == 0) ? ctx_t : (sl == 1) ? ctx_h : ctx_w;
    us8_t v = *(const us8_t*)((const unsigned short*)cp + obase
                            + (size_t)(bo * 64 + row) * THW_ + s0 + c8 * 8);
    unsigned short* dst = &As3[sl * 4352 + row * 68 + c8 * 8];
    ushort4 lo, hi;
    lo.x = v[0]; lo.y = v[1]; lo.z = v[2]; lo.w = v[3];
    hi.x = v[4]; hi.y = v[5]; hi.z = v[6]; hi.w = v[7];
    *(ushort4*)dst = lo;
    *(ushort4*)(dst + 4) = hi;
  }
  __syncthreads();

  f4_t yacc[2][2];
  #pragma unroll
  for (int mi = 0; mi < 2; mi++)
    #pragma unroll
    for (int ni = 0; ni < 2; ni++) yacc[mi][ni] = (f4_t)0.f;
  #pragma unroll
  for (int sl = 0; sl < 3; sl++){
    #pragma unroll
    for (int mi = 0; mi < 2; mi++)
      #pragma unroll
      for (int ni = 0; ni < 2; ni++)
        #pragma unroll
        for (int r = 0; r < 4; r++){
          int ol = wm * 32 + mi * 16 + kg * 4 + r;
          int sli = wn * 32 + ni * 16 + m;
          float lg = acc[sl][mi][ni][r] + gb[sl * 256 + bo * 64 + ol];
          float g = __builtin_amdgcn_rcpf(1.f + __expf(-lg));
          yacc[mi][ni][r] += g * h2f_u(As3[sl * 4352 + ol * 68 + sli]);
        }
  }

  __syncthreads();                            // ctx reads done before yT tile overwrites
  unsigned short* tile = As3;                 // [64 s][72] bf16
  #pragma unroll
  for (int mi = 0; mi < 2; mi++)
    #pragma unroll
    for (int ni = 0; ni < 2; ni++){
      int ol = wm * 32 + mi * 16 + kg * 4;
      int sl2 = wn * 32 + ni * 16 + m;
      ushort4 w4;
      w4.x = f2bf(yacc[mi][ni][0]);
      w4.y = f2bf(yacc[mi][ni][1]);
      w4.z = f2bf(yacc[mi][ni][2]);
      w4.w = f2bf(yacc[mi][ni][3]);
      *(ushort4*)&tile[sl2 * 72 + ol] = w4;
    }
  __syncthreads();
  {
    int sr = tid >> 2, oc = (tid & 3) * 16;
    us8_t v0 = *(const us8_t*)&tile[sr * 72 + oc];
    us8_t v1 = *(const us8_t*)&tile[sr * 72 + oc + 8];
    unsigned short* dst = yT + ((size_t)b * THW_ + s0 + sr) * 256 + bo * 64 + oc;
    *(us8_t*)dst = v0;
    *(us8_t*)(dst + 8) = v1;
  }
}

// ---------------- proj GEMM -> d_out (f32); XCD-swizzled ----------------
__global__ __launch_bounds__(256) void k_mfma_proj(
    const unsigned short* __restrict__ Wb, const unsigned short* __restrict__ yT,
    float* __restrict__ out)
{
  __shared__ unsigned short As[8192], Bs[8192];
  int swz = (blockIdx.x & 7) * 128 + (blockIdx.x >> 3);   // 1024 blocks
  const int bo = swz & 1;  swz >>= 1;
  const int s0 = (swz & 255) * 128;
  const int b  = swz >> 8;
  f4_t acc[4][4];
  #pragma unroll
  for (int mi = 0; mi < 4; mi++)
    #pragma unroll
    for (int ni = 0; ni < 4; ni++) acc[mi][ni] = (f4_t)0.f;
  gemm_core_b<128>(Wb, bo * 128, yT + ((size_t)b * THW_ + s0) * 256, As, Bs, acc);
  const int lane = threadIdx.x & 63, wv = threadIdx.x >> 6;
  const int wm = wv >> 1, wn = wv & 1;
  size_t obase = (size_t)(b * C_) * THW_;
  #pragma unroll
  for (int mi = 0; mi < 4; mi++)
    #pragma unroll
    for (int ni = 0; ni < 4; ni++)
      #pragma unroll
      for (int r = 0; r < 4; r++){
        int o = bo * 128 + wm * 64 + mi * 16 + (lane >> 4) * 4 + r;
        int s = s0 + wn * 64 + ni * 16 + (lane & 15);
        out[obase + (size_t)o * THW_ + s] = acc[mi][ni][r];
      }
}

// ---------------- mean over (H,W): qg[b,c,t] (q is f16) ----------------
__global__ __launch_bounds__(256) void k_mean_hw(const __half* __restrict__ q, float* __restrict__ qg){
  int bct = blockIdx.x;
  const __half2* p = (const __half2*)(q + (size_t)bct * HW_);
  __half2 v0 = p[threadIdx.x * 2], v1 = p[threadIdx.x * 2 + 1];
  float sum = __low2float(v0) + __high2float(v0) + __low2float(v1) + __high2float(v1);
  #pragma unroll
  for (int off = 32; off; off >>= 1) sum += __shfl_down(sum, off);
  __shared__ float red[4];
  int lane = threadIdx.x & 63, w = threadIdx.x >> 6;
  if (lane == 0) red[w] = sum;
  __syncthreads();
  if (threadIdx.x == 0) qg[bct] = (red[0] + red[1] + red[2] + red[3]) * (1.f / 1024.f);
}

// ---------------- mix pre: h = gelu(pre_w @ qg + pre_b) ----------------
__global__ __launch_bounds__(256) void k_mix_pre(const float* __restrict__ preW, const float* __restrict__ preB,
    const float* __restrict__ qg, float* __restrict__ hbuf){
  int b = blockIdx.x >> 5, t = blockIdx.x & 31;
  int o = threadIdx.x;
  __shared__ float qgl[256];
  qgl[o] = qg[((size_t)(b * C_ + o)) * T_ + t];
  __syncthreads();
  float a = preB[o];
  for (int c = 0; c < C_; c++) a = fmaf(preW[o * C_ + c], qgl[c], a);
  float g = 0.5f * a * (1.f + erff(a * 0.70710678118f));
  hbuf[((size_t)(b * C_ + o)) * T_ + t] = g;
}

// ---------------- mix logits + softmax over m ----------------
__global__ __launch_bounds__(256) void k_mix_alpha(const float* __restrict__ cw, const float* __restrict__ cb,
    const float* __restrict__ hbuf, float* __restrict__ alpha){
  int b = blockIdx.x >> 5, t = blockIdx.x & 31;
  int c = threadIdx.x;
  float hv[3];
  #pragma unroll
  for (int j = 0; j < 3; j++){
    int tt = t - 2 + j;
    hv[j] = (tt >= 0) ? hbuf[((size_t)(b * C_ + c)) * T_ + tt] : 0.f;
  }
  float p[3];
  #pragma unroll
  for (int m = 0; m < 3; m++){
    const float* w = cw + ((size_t)m * C_ + c) * 3;
    p[m] = w[0] * hv[0] + w[1] * hv[1] + w[2] * hv[2];
  }
  #pragma unroll
  for (int m = 0; m < 3; m++){
    #pragma unroll
    for (int off = 32; off; off >>= 1) p[m] += __shfl_down(p[m], off);
  }
  __shared__ float red[3][4];
  int lane = threadIdx.x & 63, w = threadIdx.x >> 6;
  if (lane == 0){ red[0][w] = p[0]; red[1][w] = p[1]; red[2][w] = p[2]; }
  __syncthreads();
  if (threadIdx.x == 0){
    float lg[3];
    #pragma unroll
    for (int m = 0; m < 3; m++) lg[m] = red[m][0] + red[m][1] + red[m][2] + red[m][3] + cb[m];
    float mx = fmaxf(lg[0], fmaxf(lg[1], lg[2]));
    float e0 = __expf(lg[0] - mx), e1 = __expf(lg[1] - mx), e2 = __expf(lg[2] - mx);
    float r = 1.f / (e0 + e1 + e2);
    alpha[((size_t)(b * 3 + 0)) * T_ + t] = e0 * r;
    alpha[((size_t)(b * 3 + 1)) * T_ + t] = e1 * r;
    alpha[((size_t)(b * 3 + 2)) * T_ + t] = e2 * r;
  }
}

// ---------------- alpha-mixed causal depthwise conv 3x3x3, k AND v fused in one block --------
__global__ __launch_bounds__(256) void k_conv_mix2(
    const __half* __restrict__ kin, const __half* __restrict__ vin,
    const float* __restrict__ wkb, const float* __restrict__ wvb,
    const float* __restrict__ alpha,
    __half* __restrict__ kout, __half* __restrict__ vout)
{
  int bi = blockIdx.x;
  int c = bi & 255, t = (bi >> 8) & 31, b = bi >> 13;
  __shared__ float sK[3 * 34 * 35];    // 3570 f32
  __shared__ float sV[3 * 34 * 35];
  __shared__ float wmix[2][27];
  const int tid = threadIdx.x;
  if (tid < 54){
    int which = (tid >= 27) ? 1 : 0;
    int tap = tid - 27 * which;
    const float* bank = which ? wvb : wkb;
    float sum = 0.f;
    #pragma unroll
    for (int m = 0; m < 3; m++)
      sum += alpha[((size_t)(b * 3 + m)) * T_ + t] * bank[((size_t)m * C_ + c) * 27 + tap];
    wmix[which][tap] = sum;
  }
  const size_t cbase = ((size_t)(b * C_ + c)) * T_;

  #pragma unroll
  for (int rep = 0; rep < 2; rep++){
    int job = rep * 256 + tid;
    if (job < 408){
      int half = job & 1;
      int rr = job >> 1;
      int which = (rr >= 102) ? 1 : 0;
      int r = rr - 102 * which;
      int tp = (r >= 68) ? 2 : (r >= 34) ? 1 : 0;
      int yy = r - 34 * tp;
      int tin = t - 2 + tp;
      float* dst = (which ? sV : sK) + tp * 1190 + yy * 35 + 1 + half * 16;
      bool ok = (tin >= 0) && (yy >= 1) && (yy <= 32);
      if (ok){
        const unsigned short* src = (const unsigned short*)((which ? vin : kin)
                                  + (cbase + tin) * HW_ + (size_t)(yy - 1) * 32 + half * 16);
        us8_t v0 = *(const us8_t*)src;
        us8_t v1 = *(const us8_t*)(src + 8);
        #pragma unroll
        for (int j = 0; j < 8; j++) dst[j] = h2f_u(v0[j]);
        #pragma unroll
        for (int j = 0; j < 8; j++) dst[j + 8] = h2f_u(v1[j]);
      } else {
        #pragma unroll
        for (int j = 0; j < 16; j++) dst[j] = 0.f;
      }
      if (half == 0) dst[-1] = 0.f;
      else           dst[16] = 0.f;
    }
  }
  __syncthreads();

  const int y = tid >> 3, x0 = (tid & 7) * 4;
  #pragma unroll
  for (int which = 0; which < 2; which++){
    const float* buf = which ? sV : sK;
    const float* wm = wmix[which];
    float a[4] = {0.f, 0.f, 0.f, 0.f};
    #pragma unroll
    for (int dt = 0; dt < 3; dt++){
      #pragma unroll
      for (int dy = 0; dy < 3; dy++){
        const float* row = buf + dt * 1190 + (y + dy) * 35 + x0;
        float w0 = wm[dt * 9 + dy * 3 + 0];
        float w1 = wm[dt * 9 + dy * 3 + 1];
        float w2 = wm[dt * 9 + dy * 3 + 2];
        float c0 = row[0], c1 = row[1], c2 = row[2];
        float c3 = row[3], c4 = row[4], c5 = row[5];
        a[0] = fmaf(w0, c0, fmaf(w1, c1, fmaf(w2, c2, a[0])));
        a[1] = fmaf(w0, c1, fmaf(w1, c2, fmaf(w2, c3, a[1])));
        a[2] = fmaf(w0, c2, fmaf(w1, c3, fmaf(w2, c4, a[2])));
        a[3] = fmaf(w0, c3, fmaf(w1, c4, fmaf(w2, c5, a[3])));
      }
    }
    size_t ob = (cbase + t) * HW_ + (size_t)y * 32 + x0;
    ushort4 o4;
    o4.x = f2h_u(a[0]); o4.y = f2h_u(a[1]);
    o4.z = f2h_u(a[2]); o4.w = f2h_u(a[3]);
    *(ushort4*)((unsigned short*)(which ? vout : kout) + ob) = o4;
  }
}

// ---------------- axial attention body (MFMA), 8 waves/block, one seq per wave ----------------
// LDS: Q seq*1152 stride36; K +9216 same; V 18432 + seq*1024 stride32 (aligned ushort4 paths)
// Total 26624 ushorts = 53.2 KB -> 3 blocks/CU.
template<int AXIS>
static __device__ __forceinline__ void attn_body(
    int ggrp, int outer, int head, int b, unsigned short* smem,
    const unsigned short* __restrict__ qp, const unsigned short* __restrict__ kp,
    const unsigned short* __restrict__ vp, unsigned short* ctx,
    const float* __restrict__ cosT, const float* __restrict__ sinT)
{
  const int SS = (AXIS == 0) ? HW_ : (AXIS == 1) ? 32 : 1;
  const int GS = (AXIS == 2) ? 32 : 1;
  const int OS = (AXIS == 0) ? 32 : HW_;
  const size_t base = ((size_t)(b * C_ + head * 32)) * THW_ + (size_t)outer * OS + (size_t)(ggrp * 8) * GS;
  const int tid = threadIdx.x;                    // 0..511

  if (AXIS != 2){
    int i = tid & 31, u = tid >> 5;
    size_t glo = base + (size_t)u * THW_ + (size_t)i * SS;
    size_t ghi = glo + (size_t)16 * THW_;
    us8_t ql = *(const us8_t*)(qp + glo), qh = *(const us8_t*)(qp + ghi);
    us8_t kl = *(const us8_t*)(kp + glo), kh = *(const us8_t*)(kp + ghi);
    float cv = cosT[i * 16 + u], sv = sinT[i * 16 + u];
    #pragma unroll
    for (int g = 0; g < 8; g++){
      int rb = g * 1152 + i * 36 + 2 * u;
      float a = h2f_u(ql[g]), b2 = h2f_u(qh[g]);
      *(u32*)&smem[rb] = pkrtz(a * cv - b2 * sv, fmaf(b2, cv, a * sv));
      a = h2f_u(kl[g]); b2 = h2f_u(kh[g]);
      *(u32*)&smem[9216 + rb] = pkrtz(a * cv - b2 * sv, fmaf(b2, cv, a * sv));
    }
  } else {
    int i8 = (tid & 3) * 8, g = (tid >> 2) & 7, u = tid >> 5;
    size_t glo = base + (size_t)u * THW_ + (size_t)g * GS + i8;
    size_t ghi = glo + (size_t)16 * THW_;
    us8_t ql = *(const us8_t*)(qp + glo), qh = *(const us8_t*)(qp + ghi);
    us8_t kl = *(const us8_t*)(kp + glo), kh = *(const us8_t*)(kp + ghi);
    #pragma unroll
    for (int p2 = 0; p2 < 8; p2++){
      int i = i8 + p2;
      int rb = g * 1152 + i * 36 + 2 * u;
      float cv = cosT[i * 16 + u], sv = sinT[i * 16 + u];
      float a = h2f_u(ql[p2]), b2 = h2f_u(qh[p2]);
      *(u32*)&smem[rb] = pkrtz(a * cv - b2 * sv, fmaf(b2, cv, a * sv));
      a = h2f_u(kl[p2]); b2 = h2f_u(kh[p2]);
      *(u32*)&smem[9216 + rb] = pkrtz(a * cv - b2 * sv, fmaf(b2, cv, a * sv));
    }
  }
  #pragma unroll
  for (int rep = 0; rep < 2; rep++){
    int idx2 = rep * 512 + tid;
    if (AXIS != 2){
      int i = idx2 & 31, f = idx2 >> 5;
      size_t go = base + (size_t)f * THW_ + (size_t)i * SS;
      us8_t vv = *(const us8_t*)(vp + go);
      #pragma unroll
      for (int g = 0; g < 8; g++) smem[18432 + g * 1024 + f * 32 + i] = vv[g];
    } else {
      int i8 = (idx2 & 3) * 8, g = (idx2 >> 2) & 7, f = idx2 >> 5;
      size_t go = base + (size_t)f * THW_ + (size_t)g * GS + i8;
      us8_t vv = *(const us8_t*)(vp + go);
      int rb = 18432 + g * 1024 + f * 32 + i8;
      ushort4 lo, hi;
      lo.x = vv[0]; lo.y = vv[1]; lo.z = vv[2]; lo.w = vv[3];
      hi.x = vv[4]; hi.y = vv[5]; hi.z = vv[6]; hi.w = vv[7];
      *(ushort4*)&smem[rb] = lo;
      *(ushort4*)&smem[rb + 4] = hi;
    }
  }
  __syncthreads();

  const int lane = tid & 63;
  const int seq = tid >> 6;
  const int m = lane & 15, kg = lane >> 4;

  h8_t aQ[2], bK[2], bV[2];
  #pragma unroll
  for (int t2 = 0; t2 < 2; t2++){
    union { ushort4 u4[2]; h8_t h; } uq, uk, uv;
    int rq = seq * 1152 + (t2 * 16 + m) * 36 + kg * 8;
    uq.u4[0] = *(const ushort4*)&smem[rq];
    uq.u4[1] = *(const ushort4*)&smem[rq + 4];
    uk.u4[0] = *(const ushort4*)&smem[9216 + rq];
    uk.u4[1] = *(const ushort4*)&smem[9216 + rq + 4];
    int rv = 18432 + seq * 1024 + (t2 * 16 + m) * 32 + kg * 8;
    uv.u4[0] = *(const ushort4*)&smem[rv];
    uv.u4[1] = *(const ushort4*)&smem[rv + 4];
    aQ[t2] = uq.h; bK[t2] = uk.h; bV[t2] = uv.h;
  }

  f4_t st[2][2];
  #pragma unroll
  for (int tk = 0; tk < 2; tk++)
    #pragma unroll
    for (int tq = 0; tq < 2; tq++){
      st[tk][tq] = (f4_t)0.f;
      st[tk][tq] = __builtin_amdgcn_mfma_f32_16x16x32_f16(bK[tk], aQ[tq], st[tk][tq], 0, 0, 0);
    }

  u32 pkk[2][2][2];             // [tq][tk][pair]
  #pragma unroll
  for (int tq = 0; tq < 2; tq++){
    const int i = tq * 16 + m;
    float e[2][4];
    float mx = -3.0e38f;
    #pragma unroll
    for (int tk = 0; tk < 2; tk++)
      #pragma unroll
      for (int r = 0; r < 4; r++){
        float s = st[tk][tq][r] * 0.17677669529663687f;
        if (AXIS == 0 && (tk * 16 + kg * 4 + r) > i) s = -1e30f;
        e[tk][r] = s;
        mx = fmaxf(mx, s);
      }
    mx = fmaxf(mx, __shfl_xor(mx, 16));
    mx = fmaxf(mx, __shfl_xor(mx, 32));
    float sum = 0.f;
    #pragma unroll
    for (int tk = 0; tk < 2; tk++)
      #pragma unroll
      for (int r = 0; r < 4; r++){
        e[tk][r] = __expf(e[tk][r] - mx);
        sum += e[tk][r];
      }
    sum += __shfl_xor(sum, 16);
    sum += __shfl_xor(sum, 32);
    float rinv = 1.f / sum;
    #pragma unroll
    for (int tk = 0; tk < 2; tk++){
      pkk[tq][tk][0] = pkrtz(e[tk][0] * rinv, e[tk][1] * rinv);
      pkk[tq][tk][1] = pkrtz(e[tk][2] * rinv, e[tk][3] * rinv);
    }
  }

  h8_t aP[2];
  #pragma unroll
  for (int tq = 0; tq < 2; tq++){
    union { u32 w[4]; h8_t h; } uu;
    #pragma unroll
    for (int w = 0; w < 4; w++){
      int srcLane = ((kg & 1) * 2 + (w >> 1)) * 16 + m;
      u32 v0 = __shfl(pkk[tq][0][w & 1], srcLane);
      u32 v1 = __shfl(pkk[tq][1][w & 1], srcLane);
      uu.w[w] = (kg >= 2) ? v1 : v0;
    }
    aP[tq] = uu.h;
  }

  f4_t o_[2][2];
  #pragma unroll
  for (int tq = 0; tq < 2; tq++)
    #pragma unroll
    for (int td = 0; td < 2; td++){
      o_[tq][td] = (f4_t)0.f;
      o_[tq][td] = __builtin_amdgcn_mfma_f32_16x16x32_f16(aP[tq], bV[td], o_[tq][td], 0, 0, 0);
    }

  #pragma unroll
  for (int tq = 0; tq < 2; tq++)
    #pragma unroll
    for (int td = 0; td < 2; td++){
      int i0 = tq * 16 + kg * 4, d = td * 16 + m;
      union { u32 w[2]; ushort4 v; } pk2;
      pk2.w[0] = pkrtz(o_[tq][td][0], o_[tq][td][1]);
      pk2.w[1] = pkrtz(o_[tq][td][2], o_[tq][td][3]);
      *(ushort4*)&smem[18432 + seq * 1024 + d * 32 + i0] = pk2.v;
    }
  __syncthreads();

  #pragma unroll
  for (int rep = 0; rep < 2; rep++){
    int idx2 = rep * 512 + tid;
    if (AXIS != 2){
      int i2 = idx2 & 31, f = idx2 >> 5;
      us8_t ov;
      #pragma unroll
      for (int g = 0; g < 8; g++) ov[g] = smem[18432 + g * 1024 + f * 32 + i2];
      size_t go = base + (size_t)f * THW_ + (size_t)i2 * SS;
      *(us8_t*)(ctx + go) = ov;
    } else {
      int i8 = (idx2 & 3) * 8, g2 = (idx2 >> 2) & 7, f = idx2 >> 5;
      int rb = 18432 + g2 * 1024 + f * 32 + i8;
      ushort4 lo = *(const ushort4*)&smem[rb];
      ushort4 hi = *(const ushort4*)&smem[rb + 4];
      us8_t ov;
      ov[0] = lo.x; ov[1] = lo.y; ov[2] = lo.z; ov[3] = lo.w;
      ov[4] = hi.x; ov[5] = hi.y; ov[6] = hi.z; ov[7] = hi.w;
      size_t go = base + (size_t)f * THW_ + (size_t)g2 * GS + i8;
      *(us8_t*)(ctx + go) = ov;
    }
  }
}

// ---------------- fused attention dispatcher: sequential axes ----------------
__global__ __launch_bounds__(512) void k_attn_all(
    const __half* __restrict__ qg_, const __half* __restrict__ kg_,
    const __half* __restrict__ vg_,
    __half* __restrict__ ctx_t, __half* __restrict__ ctx_h, __half* __restrict__ ctx_w,
    const float* __restrict__ cosT, const float* __restrict__ sinT)
{
  __shared__ __align__(16) unsigned short smem[26624];   // 53.2 KB -> 3 blocks/CU
  const unsigned short* qp = (const unsigned short*)qg_;
  const unsigned short* kp = (const unsigned short*)kg_;
  const unsigned short* vp = (const unsigned short*)vg_;
  int ax = blockIdx.x >> 11;
  int id = blockIdx.x & 2047;
  int ggrp = (id >> 3) & 3;
  int rest = ((id >> 5) << 3) | (id & 7);
  int outer = rest & 31, head = (rest >> 5) & 7, b = rest >> 8;
  if (ax == 0)      attn_body<0>(ggrp, outer, head, b, smem, qp, kp, vp, (unsigned short*)ctx_t, cosT, sinT);
  else if (ax == 1) attn_body<1>(ggrp, outer, head, b, smem, qp, kp, vp, (unsigned short*)ctx_h, cosT, sinT);
  else              attn_body<2>(ggrp, outer, head, b, smem, qp, kp, vp, (unsigned short*)ctx_w, cosT, sinT);
}

extern "C" void kernel_launch(void* const* d_in, const int* in_sizes, int n_in,
                              void* d_out, int out_size, void* d_ws, size_t ws_size,
                              hipStream_t stream)
{
  (void)in_sizes; (void)n_in; (void)out_size; (void)ws_size;
  const float* x       = (const float*)d_in[0];
  const float* w_qkv   = (const float*)d_in[1];
  const float* wk_bank = (const float*)d_in[2];
  const float* wv_bank = (const float*)d_in[3];
  const float* pre_w   = (const float*)d_in[4];
  const float* pre_b   = (const float*)d_in[5];
  const float* cw      = (const float*)d_in[6];
  const float* cb      = (const float*)d_in[7];
  const float* gate_w  = (const float*)d_in[8];
  const float* gate_b  = (const float*)d_in[9];
  const float* proj_w  = (const float*)d_in[10];

  const size_t SZ = (size_t)B_ * C_ * THW_;           // 16,777,216 elems
  __half* hb = (__half*)d_ws;                         // 32MB slots
  unsigned short* xT  = (unsigned short*)(hb + 0 * SZ);  // bf16, alive to gate
  __half* qH   = hb + 1 * SZ;                         // q
  __half* kH   = hb + 2 * SZ;                         // k -> ctx_t
  __half* vH   = hb + 3 * SZ;                         // v -> ctx_h
  __half* koH  = hb + 4 * SZ;                         // k_out -> yT(bf16)
  __half* voH  = hb + 5 * SZ;                         // v_out (stays valid)
  __half* ctxtH = kH;
  __half* ctxhH = vH;
  __half* ctxwH = (__half*)d_out;                     // ctx_w in d_out (dead until proj)
  unsigned short* yT = (unsigned short*)koH;          // over dead k_out
  float* sm    = (float*)(hb + 6 * SZ);               // smalls
  float* qg    = sm;                                  // 16384
  float* hbuf  = qg + 16384;                          // 16384
  float* alpha = hbuf + 16384;                        // 192
  float* cosT  = alpha + 192;                         // 512
  float* sinT  = cosT + 512;                          // 512
  unsigned short* wB = (unsigned short*)(sinT + 512); // 1792*256 bf16 (896 KB)
  unsigned short* wBq = wB;                           // [768][256]
  unsigned short* wBg = wB + 768 * 256;               // [768][256]
  unsigned short* wBp = wB + 1536 * 256;              // [256][256]

  k_rope_table<<<1, 512, 0, stream>>>(cosT, sinT);
  k_wcvt<<<1792, 256, 0, stream>>>(w_qkv, gate_w, proj_w, wB);
  k_transpose_cvt<float><<<dim3(512, 4, 2), 256, 0, stream>>>(x, xT);

  k_mfma_qkv<<<3072, 256, 0, stream>>>(wBq, xT, qH, kH, vH);

  k_mean_hw<<<16384, 256, 0, stream>>>(qH, qg);
  k_mix_pre<<<64, 256, 0, stream>>>(pre_w, pre_b, qg, hbuf);
  k_mix_alpha<<<64, 256, 0, stream>>>(cw, cb, hbuf, alpha);

  k_conv_mix2<<<16384, 256, 0, stream>>>(kH, vH, wk_bank, wv_bank, alpha, koH, voH);

  k_attn_all<<<6144, 512, 0, stream>>>(qH, koH, voH, ctxtH, ctxhH, ctxwH, cosT, sinT);

  k_mfma_gate2<<<4096, 256, 0, stream>>>(wBg, xT, gate_b,
                                         ctxtH, ctxhH, ctxwH, yT); // yT over dead k_out
  k_mfma_proj<<<1024, 256, 0, stream>>>(wBp, yT, (float*)d_out);
}

// Round 18
// 342.170 us; speedup vs baseline: 1.0676x; 1.0676x over previous
//
#include <hip/hip_runtime.h>
#include <hip/hip_fp16.h>
#include <math.h>

#define B_   2
#define C_   256
#define T_   32
#define HW_  1024
#define THW_ 32768

using u32 = unsigned int;
typedef __attribute__((ext_vector_type(8))) short bf8_t;   // 8 bf16 in 4 VGPRs
typedef __attribute__((ext_vector_type(8))) unsigned short us8_t;
typedef __attribute__((ext_vector_type(8))) _Float16 h8_t; // 8 f16 in 4 VGPRs
typedef __attribute__((ext_vector_type(2))) __fp16 fp16v2; // builtin cvt_pkrtz return type
typedef __attribute__((ext_vector_type(4))) float f4_t;

static __device__ __forceinline__ unsigned short f2bf(float x){
  u32 u = __float_as_uint(x);
  u32 r = (u + 0x7FFF + ((u >> 16) & 1)) >> 16;   // RNE
  return (unsigned short)r;
}
static __device__ __forceinline__ float h2f_u(unsigned short u){
  union { __half h; unsigned short us; } cv; cv.us = u; return __half2float(cv.h);
}
static __device__ __forceinline__ unsigned short f2h_u(float f){
  union { __half h; unsigned short us; } cv; cv.h = __float2half(f); return cv.us;
}
static __device__ __forceinline__ u32 pkrtz(float a, float b){
  union { fp16v2 h; u32 w; } cv; cv.h = __builtin_amdgcn_cvt_pkrtz(a, b); return cv.w;
}
static __device__ __forceinline__ float ldf(const float* p){ return *p; }
static __device__ __forceinline__ float ldf(const __half* p){ return __half2float(*p); }

// ---------------- rope table ----------------
__global__ void k_rope_table(float* __restrict__ cosT, float* __restrict__ sinT){
  int tid = threadIdx.x;            // 512 threads, tid = i*16+u
  int i = tid >> 4, u = tid & 15;
  float invf = powf(10000.f, -(2.f * (float)u) / 32.f);
  float s, c;
  sincosf((float)i * invf, &s, &c);
  cosT[tid] = c;
  sinT[tid] = s;
}

// ---------------- weight cvt: stack w_qkv(768), gate_w(768), proj_w(256) as bf16 [1792][256] --
__global__ void k_wcvt(const float* __restrict__ w_qkv, const float* __restrict__ gate_w,
                       const float* __restrict__ proj_w, unsigned short* __restrict__ out){
  int row = blockIdx.x, c = threadIdx.x;
  const float* src = (row < 768) ? w_qkv + (size_t)row * 256
                   : (row < 1536) ? gate_w + (size_t)(row - 768) * 256
                                  : proj_w + (size_t)(row - 1536) * 256;
  out[(size_t)row * 256 + c] = f2bf(src[c]);
}

// ---------------- transpose+cvt: [b][256][THW] f32 -> bf16 [b][THW][256] ----------------
template<typename InT>
__global__ __launch_bounds__(256) void k_transpose_cvt(
    const InT* __restrict__ in, unsigned short* __restrict__ outT)
{
  __shared__ float tile[64][65];
  int s0 = blockIdx.x * 64;     // 512
  int c0 = blockIdx.y * 64;     // 4
  int b  = blockIdx.z;
  int tid = threadIdx.x;
  for (int idx = tid; idx < 4096; idx += 256){
    int c = idx >> 6, s = idx & 63;
    tile[c][s] = ldf(&in[((size_t)(b * C_ + c0 + c)) * THW_ + s0 + s]);
  }
  __syncthreads();
  for (int idx = tid; idx < 4096; idx += 256){
    int s = idx >> 6, c = idx & 63;
    outT[((size_t)b * THW_ + s0 + s) * 256 + c0 + c] = f2bf(tile[c][s]);
  }
}

// ---------------- MFMA GEMM core (bf16 A bank): 128xBN tile, K=256 ----------------
template<int BN>
static __device__ __forceinline__ void gemm_core_b(
    const unsigned short* __restrict__ A, int o0,
    const unsigned short* __restrict__ BT,   // pre-offset: + (b*THW + s0)*256
    unsigned short* As, unsigned short* Bs, f4_t acc[4][BN / 32])
{
  const int tid = threadIdx.x;
  const int lane = tid & 63, wv = tid >> 6;
  const int wm = wv >> 1, wn = wv & 1;
  const int m = lane & 15, kg = lane >> 4;
  const int arow = tid >> 1, aseg = (tid & 1) * 64;     // A: 128 rows, 2 thr/row, 64B each
  const int brow = (BN == 128) ? (tid >> 1) : (tid >> 2);
  const int bseg = (BN == 128) ? (tid & 1) * 64 : (tid & 3) * 32;
  for (int ks = 0; ks < 4; ks++){
    __syncthreads();                                    // protect prior reads
    {
      const unsigned short* ga = A + (size_t)(o0 + arow) * 256 + ks * 64 + aseg / 2;
      #pragma unroll
      for (int q2 = 0; q2 < 4; q2++){
        us8_t v = *(const us8_t*)(ga + q2 * 8);
        *(us8_t*)((char*)As + arow * 128 + ((aseg + q2 * 16) ^ ((arow & 7) << 4))) = v;
      }
      const unsigned short* gb = BT + (size_t)brow * 256 + ks * 64 + bseg / 2;
      #pragma unroll
      for (int q2 = 0; q2 < (BN == 128 ? 4 : 2); q2++){
        us8_t v = *(const us8_t*)(gb + q2 * 8);
        *(us8_t*)((char*)Bs + brow * 128 + ((bseg + q2 * 16) ^ ((brow & 7) << 4))) = v;
      }
    }
    __syncthreads();
    #pragma unroll
    for (int kk = 0; kk < 2; kk++){
      bf8_t af[4], bfr[BN / 32];
      #pragma unroll
      for (int mi = 0; mi < 4; mi++){
        int row = wm * 64 + mi * 16 + m;
        af[mi] = *(const bf8_t*)((const char*)As + row * 128 + ((kk * 64 + kg * 16) ^ ((row & 7) << 4)));
      }
      #pragma unroll
      for (int ni = 0; ni < BN / 32; ni++){
        int row = wn * (BN / 2) + ni * 16 + m;
        bfr[ni] = *(const bf8_t*)((const char*)Bs + row * 128 + ((kk * 64 + kg * 16) ^ ((row & 7) << 4)));
      }
      #pragma unroll
      for (int mi = 0; mi < 4; mi++)
        #pragma unroll
        for (int ni = 0; ni < BN / 32; ni++)
          acc[mi][ni] = __builtin_amdgcn_mfma_f32_16x16x32_bf16(af[mi], bfr[ni], acc[mi][ni], 0, 0, 0);
    }
  }
}

// ---------------- qkv GEMM: Wq(bf16)[768][256] @ x -> q,k,v (f16); fused q-mean ----------
__global__ __launch_bounds__(256) void k_mfma_qkv(
    const unsigned short* __restrict__ Wb, const unsigned short* __restrict__ xT,
    __half* __restrict__ q, __half* __restrict__ k, __half* __restrict__ v,
    float* __restrict__ qg)
{
  __shared__ unsigned short As[8192], Bs[8192];
  int swz = (blockIdx.x & 7) * 384 + (blockIdx.x >> 3);   // 3072 blocks, %8==0
  const int bo = swz % 6;  swz /= 6;
  const int s0 = (swz & 255) * 128;
  const int b  = swz >> 8;
  f4_t acc[4][4];
  #pragma unroll
  for (int mi = 0; mi < 4; mi++)
    #pragma unroll
    for (int ni = 0; ni < 4; ni++) acc[mi][ni] = (f4_t)0.f;
  gemm_core_b<128>(Wb, bo * 128, xT + ((size_t)b * THW_ + s0) * 256, As, Bs, acc);
  __half* outp = (bo < 2) ? q : (bo < 4) ? k : v;
  const int ro = (bo & 1) * 128;
  const int lane = threadIdx.x & 63, wv = threadIdx.x >> 6;
  const int wm = wv >> 1, wn = wv & 1;
  size_t obase = (size_t)(b * C_) * THW_;
  #pragma unroll
  for (int mi = 0; mi < 4; mi++)
    #pragma unroll
    for (int ni = 0; ni < 4; ni++)
      #pragma unroll
      for (int r = 0; r < 4; r++){
        int o = ro + wm * 64 + mi * 16 + (lane >> 4) * 4 + r;
        int s = s0 + wn * 64 + ni * 16 + (lane & 15);
        outp[obase + (size_t)o * THW_ + s] = __float2half(acc[mi][ni][r]);
      }
  // fused mean over (h,w) for q slices: block's 128 s-cols lie within one t.
  if (bo < 2){
    const int t = s0 >> 10;
    #pragma unroll
    for (int mi = 0; mi < 4; mi++)
      #pragma unroll
      for (int r = 0; r < 4; r++){
        float sum = acc[mi][0][r] + acc[mi][1][r] + acc[mi][2][r] + acc[mi][3][r];
        sum += __shfl_xor(sum, 1);
        sum += __shfl_xor(sum, 2);
        sum += __shfl_xor(sum, 4);
        sum += __shfl_xor(sum, 8);
        if ((lane & 15) == 0){
          int o = ro + wm * 64 + mi * 16 + (lane >> 4) * 4 + r;
          atomicAdd(&qg[((size_t)(b * C_ + o)) * T_ + t], sum * (1.f / 1024.f));
        }
      }
  }
}

// ---------------- gate GEMM + sigmoid + combine, 3 slices, yT direct; LDS-staged ctx --------
__global__ __launch_bounds__(256) void k_mfma_gate2(
    const unsigned short* __restrict__ Wb,   // bf16 gate bank [768][256]
    const unsigned short* __restrict__ xT,
    const float* __restrict__ gb,
    const __half* __restrict__ ctx_t, const __half* __restrict__ ctx_h,
    const __half* __restrict__ ctx_w,
    unsigned short* __restrict__ yT)         // bf16 [b][THW][256]
{
  __shared__ unsigned short As3[13056];      // main loop: 3x4096 W tiles; epilogue: 3x[64][68] ctx
  __shared__ unsigned short Bs[4096];
  int swz = (blockIdx.x & 7) * 512 + (blockIdx.x >> 3);   // 4096 blocks
  const int bo = swz & 3;  swz >>= 2;
  const int s0 = (swz & 511) * 64;
  const int b  = swz >> 9;
  const int tid = threadIdx.x;
  const int lane = tid & 63, wv = tid >> 6;
  const int wm = wv >> 1, wn = wv & 1;
  const int m = lane & 15, kg = lane >> 4;
  const unsigned short* xbase = xT + ((size_t)b * THW_ + s0) * 256;
  const size_t obase = (size_t)(b * C_) * THW_;

  f4_t acc[3][2][2];
  #pragma unroll
  for (int sl = 0; sl < 3; sl++)
    #pragma unroll
    for (int mi = 0; mi < 2; mi++)
      #pragma unroll
      for (int ni = 0; ni < 2; ni++) acc[sl][mi][ni] = (f4_t)0.f;

  for (int ks = 0; ks < 4; ks++){
    __syncthreads();
    #pragma unroll
    for (int rep = 0; rep < 2; rep++){
      int idx = rep * 256 + tid;              // 0..511
      int row = idx >> 3, seg = idx & 7;
      us8_t v = *(const us8_t*)(xbase + (size_t)row * 256 + ks * 64 + seg * 8);
      *(us8_t*)((char*)Bs + row * 128 + ((seg * 16) ^ ((row & 7) << 4))) = v;
    }
    #pragma unroll
    for (int sl = 0; sl < 3; sl++){
      #pragma unroll
      for (int rep = 0; rep < 2; rep++){
        int idx = rep * 256 + tid;
        int row = idx >> 3, seg = idx & 7;
        us8_t v = *(const us8_t*)(Wb + (size_t)(sl * 256 + bo * 64 + row) * 256 + ks * 64 + seg * 8);
        *(us8_t*)((char*)As3 + sl * 8192 + row * 128 + ((seg * 16) ^ ((row & 7) << 4))) = v;
      }
    }
    __syncthreads();
    #pragma unroll
    for (int kk = 0; kk < 2; kk++){
      bf8_t bfr[2], af[3][2];
      #pragma unroll
      for (int ni = 0; ni < 2; ni++){
        int row = wn * 32 + ni * 16 + m;
        bfr[ni] = *(const bf8_t*)((const char*)Bs + row * 128 + ((kk * 64 + kg * 16) ^ ((row & 7) << 4)));
      }
      #pragma unroll
      for (int sl = 0; sl < 3; sl++)
        #pragma unroll
        for (int mi = 0; mi < 2; mi++){
          int row = wm * 32 + mi * 16 + m;
          af[sl][mi] = *(const bf8_t*)((const char*)As3 + sl * 8192 + row * 128 + ((kk * 64 + kg * 16) ^ ((row & 7) << 4)));
        }
      #pragma unroll
      for (int sl = 0; sl < 3; sl++)
        #pragma unroll
        for (int mi = 0; mi < 2; mi++)
          #pragma unroll
          for (int ni = 0; ni < 2; ni++)
            acc[sl][mi][ni] = __builtin_amdgcn_mfma_f32_16x16x32_bf16(af[sl][mi], bfr[ni], acc[sl][mi][ni], 0, 0, 0);
    }
  }

  // ---- stage ctx tiles into LDS: 3 slices x [64 o][68 stride] f16, us8 global loads ----
  __syncthreads();                            // MFMA reads of As3 done
  #pragma unroll
  for (int rep = 0; rep < 6; rep++){
    int job = rep * 256 + tid;                // 0..1535 = sl(3) x row(64) x c8(8)
    int sl = job >> 9;
    int row = (job >> 3) & 63;
    int c8 = job & 7;
    const __half* cp = (sl == 0) ? ctx_t : (sl == 1) ? ctx_h : ctx_w;
    us8_t v = *(const us8_t*)((const unsigned short*)cp + obase
                            + (size_t)(bo * 64 + row) * THW_ + s0 + c8 * 8);
    unsigned short* dst = &As3[sl * 4352 + row * 68 + c8 * 8];
    ushort4 lo, hi;
    lo.x = v[0]; lo.y = v[1]; lo.z = v[2]; lo.w = v[3];
    hi.x = v[4]; hi.y = v[5]; hi.z = v[6]; hi.w = v[7];
    *(ushort4*)dst = lo;
    *(ushort4*)(dst + 4) = hi;
  }
  __syncthreads();

  f4_t yacc[2][2];
  #pragma unroll
  for (int mi = 0; mi < 2; mi++)
    #pragma unroll
    for (int ni = 0; ni < 2; ni++) yacc[mi][ni] = (f4_t)0.f;
  #pragma unroll
  for (int sl = 0; sl < 3; sl++){
    #pragma unroll
    for (int mi = 0; mi < 2; mi++)
      #pragma unroll
      for (int ni = 0; ni < 2; ni++)
        #pragma unroll
        for (int r = 0; r < 4; r++){
          int ol = wm * 32 + mi * 16 + kg * 4 + r;
          int sli = wn * 32 + ni * 16 + m;
          float lg = acc[sl][mi][ni][r] + gb[sl * 256 + bo * 64 + ol];
          float g = __builtin_amdgcn_rcpf(1.f + __expf(-lg));
          yacc[mi][ni][r] += g * h2f_u(As3[sl * 4352 + ol * 68 + sli]);
        }
  }

  __syncthreads();                            // ctx reads done before yT tile overwrites
  unsigned short* tile = As3;                 // [64 s][72] bf16
  #pragma unroll
  for (int mi = 0; mi < 2; mi++)
    #pragma unroll
    for (int ni = 0; ni < 2; ni++){
      int ol = wm * 32 + mi * 16 + kg * 4;
      int sl2 = wn * 32 + ni * 16 + m;
      ushort4 w4;
      w4.x = f2bf(yacc[mi][ni][0]);
      w4.y = f2bf(yacc[mi][ni][1]);
      w4.z = f2bf(yacc[mi][ni][2]);
      w4.w = f2bf(yacc[mi][ni][3]);
      *(ushort4*)&tile[sl2 * 72 + ol] = w4;
    }
  __syncthreads();
  {
    int sr = tid >> 2, oc = (tid & 3) * 16;
    us8_t v0 = *(const us8_t*)&tile[sr * 72 + oc];
    us8_t v1 = *(const us8_t*)&tile[sr * 72 + oc + 8];
    unsigned short* dst = yT + ((size_t)b * THW_ + s0 + sr) * 256 + bo * 64 + oc;
    *(us8_t*)dst = v0;
    *(us8_t*)(dst + 8) = v1;
  }
}

// ---------------- proj GEMM -> d_out (f32); XCD-swizzled ----------------
__global__ __launch_bounds__(256) void k_mfma_proj(
    const unsigned short* __restrict__ Wb, const unsigned short* __restrict__ yT,
    float* __restrict__ out)
{
  __shared__ unsigned short As[8192], Bs[8192];
  int swz = (blockIdx.x & 7) * 128 + (blockIdx.x >> 3);   // 1024 blocks
  const int bo = swz & 1;  swz >>= 1;
  const int s0 = (swz & 255) * 128;
  const int b  = swz >> 8;
  f4_t acc[4][4];
  #pragma unroll
  for (int mi = 0; mi < 4; mi++)
    #pragma unroll
    for (int ni = 0; ni < 4; ni++) acc[mi][ni] = (f4_t)0.f;
  gemm_core_b<128>(Wb, bo * 128, yT + ((size_t)b * THW_ + s0) * 256, As, Bs, acc);
  const int lane = threadIdx.x & 63, wv = threadIdx.x >> 6;
  const int wm = wv >> 1, wn = wv & 1;
  size_t obase = (size_t)(b * C_) * THW_;
  #pragma unroll
  for (int mi = 0; mi < 4; mi++)
    #pragma unroll
    for (int ni = 0; ni < 4; ni++)
      #pragma unroll
      for (int r = 0; r < 4; r++){
        int o = bo * 128 + wm * 64 + mi * 16 + (lane >> 4) * 4 + r;
        int s = s0 + wn * 64 + ni * 16 + (lane & 15);
        out[obase + (size_t)o * THW_ + s] = acc[mi][ni][r];
      }
}

// ---------------- mix pre: h = gelu(pre_w @ qg + pre_b) ----------------
__global__ __launch_bounds__(256) void k_mix_pre(const float* __restrict__ preW, const float* __restrict__ preB,
    const float* __restrict__ qg, float* __restrict__ hbuf){
  int b = blockIdx.x >> 5, t = blockIdx.x & 31;
  int o = threadIdx.x;
  __shared__ float qgl[256];
  qgl[o] = qg[((size_t)(b * C_ + o)) * T_ + t];
  __syncthreads();
  float a = preB[o];
  for (int c = 0; c < C_; c++) a = fmaf(preW[o * C_ + c], qgl[c], a);
  float g = 0.5f * a * (1.f + erff(a * 0.70710678118f));
  hbuf[((size_t)(b * C_ + o)) * T_ + t] = g;
}

// ---------------- mix logits + softmax over m ----------------
__global__ __launch_bounds__(256) void k_mix_alpha(const float* __restrict__ cw, const float* __restrict__ cb,
    const float* __restrict__ hbuf, float* __restrict__ alpha){
  int b = blockIdx.x >> 5, t = blockIdx.x & 31;
  int c = threadIdx.x;
  float hv[3];
  #pragma unroll
  for (int j = 0; j < 3; j++){
    int tt = t - 2 + j;
    hv[j] = (tt >= 0) ? hbuf[((size_t)(b * C_ + c)) * T_ + tt] : 0.f;
  }
  float p[3];
  #pragma unroll
  for (int m = 0; m < 3; m++){
    const float* w = cw + ((size_t)m * C_ + c) * 3;
    p[m] = w[0] * hv[0] + w[1] * hv[1] + w[2] * hv[2];
  }
  #pragma unroll
  for (int m = 0; m < 3; m++){
    #pragma unroll
    for (int off = 32; off; off >>= 1) p[m] += __shfl_down(p[m], off);
  }
  __shared__ float red[3][4];
  int lane = threadIdx.x & 63, w = threadIdx.x >> 6;
  if (lane == 0){ red[0][w] = p[0]; red[1][w] = p[1]; red[2][w] = p[2]; }
  __syncthreads();
  if (threadIdx.x == 0){
    float lg[3];
    #pragma unroll
    for (int m = 0; m < 3; m++) lg[m] = red[m][0] + red[m][1] + red[m][2] + red[m][3] + cb[m];
    float mx = fmaxf(lg[0], fmaxf(lg[1], lg[2]));
    float e0 = __expf(lg[0] - mx), e1 = __expf(lg[1] - mx), e2 = __expf(lg[2] - mx);
    float r = 1.f / (e0 + e1 + e2);
    alpha[((size_t)(b * 3 + 0)) * T_ + t] = e0 * r;
    alpha[((size_t)(b * 3 + 1)) * T_ + t] = e1 * r;
    alpha[((size_t)(b * 3 + 2)) * T_ + t] = e2 * r;
  }
}

// ---------------- alpha-mixed causal depthwise conv 3x3x3, k AND v fused in one block --------
__global__ __launch_bounds__(256) void k_conv_mix2(
    const __half* __restrict__ kin, const __half* __restrict__ vin,
    const float* __restrict__ wkb, const float* __restrict__ wvb,
    const float* __restrict__ alpha,
    __half* __restrict__ kout, __half* __restrict__ vout)
{
  int bi = blockIdx.x;
  int c = bi & 255, t = (bi >> 8) & 31, b = bi >> 13;
  __shared__ float sK[3 * 34 * 35];    // 3570 f32
  __shared__ float sV[3 * 34 * 35];
  __shared__ float wmix[2][27];
  const int tid = threadIdx.x;
  if (tid < 54){
    int which = (tid >= 27) ? 1 : 0;
    int tap = tid - 27 * which;
    const float* bank = which ? wvb : wkb;
    float sum = 0.f;
    #pragma unroll
    for (int m = 0; m < 3; m++)
      sum += alpha[((size_t)(b * 3 + m)) * T_ + t] * bank[((size_t)m * C_ + c) * 27 + tap];
    wmix[which][tap] = sum;
  }
  const size_t cbase = ((size_t)(b * C_ + c)) * T_;

  #pragma unroll
  for (int rep = 0; rep < 2; rep++){
    int job = rep * 256 + tid;
    if (job < 408){
      int half = job & 1;
      int rr = job >> 1;
      int which = (rr >= 102) ? 1 : 0;
      int r = rr - 102 * which;
      int tp = (r >= 68) ? 2 : (r >= 34) ? 1 : 0;
      int yy = r - 34 * tp;
      int tin = t - 2 + tp;
      float* dst = (which ? sV : sK) + tp * 1190 + yy * 35 + 1 + half * 16;
      bool ok = (tin >= 0) && (yy >= 1) && (yy <= 32);
      if (ok){
        const unsigned short* src = (const unsigned short*)((which ? vin : kin)
                                  + (cbase + tin) * HW_ + (size_t)(yy - 1) * 32 + half * 16);
        us8_t v0 = *(const us8_t*)src;
        us8_t v1 = *(const us8_t*)(src + 8);
        #pragma unroll
        for (int j = 0; j < 8; j++) dst[j] = h2f_u(v0[j]);
        #pragma unroll
        for (int j = 0; j < 8; j++) dst[j + 8] = h2f_u(v1[j]);
      } else {
        #pragma unroll
        for (int j = 0; j < 16; j++) dst[j] = 0.f;
      }
      if (half == 0) dst[-1] = 0.f;
      else           dst[16] = 0.f;
    }
  }
  __syncthreads();

  const int y = tid >> 3, x0 = (tid & 7) * 4;
  #pragma unroll
  for (int which = 0; which < 2; which++){
    const float* buf = which ? sV : sK;
    const float* wm = wmix[which];
    float a[4] = {0.f, 0.f, 0.f, 0.f};
    #pragma unroll
    for (int dt = 0; dt < 3; dt++){
      #pragma unroll
      for (int dy = 0; dy < 3; dy++){
        const float* row = buf + dt * 1190 + (y + dy) * 35 + x0;
        float w0 = wm[dt * 9 + dy * 3 + 0];
        float w1 = wm[dt * 9 + dy * 3 + 1];
        float w2 = wm[dt * 9 + dy * 3 + 2];
        float c0 = row[0], c1 = row[1], c2 = row[2];
        float c3 = row[3], c4 = row[4], c5 = row[5];
        a[0] = fmaf(w0, c0, fmaf(w1, c1, fmaf(w2, c2, a[0])));
        a[1] = fmaf(w0, c1, fmaf(w1, c2, fmaf(w2, c3, a[1])));
        a[2] = fmaf(w0, c2, fmaf(w1, c3, fmaf(w2, c4, a[2])));
        a[3] = fmaf(w0, c3, fmaf(w1, c4, fmaf(w2, c5, a[3])));
      }
    }
    size_t ob = (cbase + t) * HW_ + (size_t)y * 32 + x0;
    ushort4 o4;
    o4.x = f2h_u(a[0]); o4.y = f2h_u(a[1]);
    o4.z = f2h_u(a[2]); o4.w = f2h_u(a[3]);
    *(ushort4*)((unsigned short*)(which ? vout : kout) + ob) = o4;
  }
}

// ---------------- axial attention body (MFMA), 8 waves/block, one seq per wave ----------------
// r16 layout: Q seq*1152 stride36; K +9216; V 18432 + seq*1152 stride36. 55.3 KB.
template<int AXIS>
static __device__ __forceinline__ void attn_body(
    int ggrp, int outer, int head, int b, unsigned short* smem,
    const unsigned short* __restrict__ qp, const unsigned short* __restrict__ kp,
    const unsigned short* __restrict__ vp, unsigned short* ctx,
    const float* __restrict__ cosT, const float* __restrict__ sinT)
{
  const int SS = (AXIS == 0) ? HW_ : (AXIS == 1) ? 32 : 1;
  const int GS = (AXIS == 2) ? 32 : 1;
  const int OS = (AXIS == 0) ? 32 : HW_;
  const size_t base = ((size_t)(b * C_ + head * 32)) * THW_ + (size_t)outer * OS + (size_t)(ggrp * 8) * GS;
  const int tid = threadIdx.x;                    // 0..511

  if (AXIS != 2){
    int i = tid & 31, u = tid >> 5;
    size_t glo = base + (size_t)u * THW_ + (size_t)i * SS;
    size_t ghi = glo + (size_t)16 * THW_;
    us8_t ql = *(const us8_t*)(qp + glo), qh = *(const us8_t*)(qp + ghi);
    us8_t kl = *(const us8_t*)(kp + glo), kh = *(const us8_t*)(kp + ghi);
    float cv = cosT[i * 16 + u], sv = sinT[i * 16 + u];
    #pragma unroll
    for (int g = 0; g < 8; g++){
      int rb = g * 1152 + i * 36 + 2 * u;
      float a = h2f_u(ql[g]), b2 = h2f_u(qh[g]);
      *(u32*)&smem[rb] = pkrtz(a * cv - b2 * sv, fmaf(b2, cv, a * sv));
      a = h2f_u(kl[g]); b2 = h2f_u(kh[g]);
      *(u32*)&smem[9216 + rb] = pkrtz(a * cv - b2 * sv, fmaf(b2, cv, a * sv));
    }
  } else {
    int i8 = (tid & 3) * 8, g = (tid >> 2) & 7, u = tid >> 5;
    size_t glo = base + (size_t)u * THW_ + (size_t)g * GS + i8;
    size_t ghi = glo + (size_t)16 * THW_;
    us8_t ql = *(const us8_t*)(qp + glo), qh = *(const us8_t*)(qp + ghi);
    us8_t kl = *(const us8_t*)(kp + glo), kh = *(const us8_t*)(kp + ghi);
    #pragma unroll
    for (int p2 = 0; p2 < 8; p2++){
      int i = i8 + p2;
      int rb = g * 1152 + i * 36 + 2 * u;
      float cv = cosT[i * 16 + u], sv = sinT[i * 16 + u];
      float a = h2f_u(ql[p2]), b2 = h2f_u(qh[p2]);
      *(u32*)&smem[rb] = pkrtz(a * cv - b2 * sv, fmaf(b2, cv, a * sv));
      a = h2f_u(kl[p2]); b2 = h2f_u(kh[p2]);
      *(u32*)&smem[9216 + rb] = pkrtz(a * cv - b2 * sv, fmaf(b2, cv, a * sv));
    }
  }
  #pragma unroll
  for (int rep = 0; rep < 2; rep++){
    int idx2 = rep * 512 + tid;
    if (AXIS != 2){
      int i = idx2 & 31, f = idx2 >> 5;
      size_t go = base + (size_t)f * THW_ + (size_t)i * SS;
      us8_t vv = *(const us8_t*)(vp + go);
      #pragma unroll
      for (int g = 0; g < 8; g++) smem[18432 + g * 1152 + f * 36 + i] = vv[g];
    } else {
      int i8 = (idx2 & 3) * 8, g = (idx2 >> 2) & 7, f = idx2 >> 5;
      size_t go = base + (size_t)f * THW_ + (size_t)g * GS + i8;
      us8_t vv = *(const us8_t*)(vp + go);
      int rb = 18432 + g * 1152 + f * 36 + i8;
      ushort4 lo, hi;
      lo.x = vv[0]; lo.y = vv[1]; lo.z = vv[2]; lo.w = vv[3];
      hi.x = vv[4]; hi.y = vv[5]; hi.z = vv[6]; hi.w = vv[7];
      *(ushort4*)&smem[rb] = lo;
      *(ushort4*)&smem[rb + 4] = hi;
    }
  }
  __syncthreads();

  const int lane = tid & 63;
  const int seq = tid >> 6;
  const int m = lane & 15, kg = lane >> 4;

  h8_t aQ[2], bK[2], bV[2];
  #pragma unroll
  for (int t2 = 0; t2 < 2; t2++){
    union { ushort4 u4[2]; h8_t h; } uq, uk, uv;
    int rq = seq * 1152 + (t2 * 16 + m) * 36 + kg * 8;
    uq.u4[0] = *(const ushort4*)&smem[rq];
    uq.u4[1] = *(const ushort4*)&smem[rq + 4];
    uk.u4[0] = *(const ushort4*)&smem[9216 + rq];
    uk.u4[1] = *(const ushort4*)&smem[9216 + rq + 4];
    uv.u4[0] = *(const ushort4*)&smem[18432 + rq];
    uv.u4[1] = *(const ushort4*)&smem[18432 + rq + 4];
    aQ[t2] = uq.h; bK[t2] = uk.h; bV[t2] = uv.h;
  }

  f4_t st[2][2];
  #pragma unroll
  for (int tk = 0; tk < 2; tk++)
    #pragma unroll
    for (int tq = 0; tq < 2; tq++){
      st[tk][tq] = (f4_t)0.f;
      st[tk][tq] = __builtin_amdgcn_mfma_f32_16x16x32_f16(bK[tk], aQ[tq], st[tk][tq], 0, 0, 0);
    }

  u32 pkk[2][2][2];             // [tq][tk][pair]
  #pragma unroll
  for (int tq = 0; tq < 2; tq++){
    const int i = tq * 16 + m;
    float e[2][4];
    float mx = -3.0e38f;
    #pragma unroll
    for (int tk = 0; tk < 2; tk++)
      #pragma unroll
      for (int r = 0; r < 4; r++){
        float s = st[tk][tq][r] * 0.17677669529663687f;
        if (AXIS == 0 && (tk * 16 + kg * 4 + r) > i) s = -1e30f;
        e[tk][r] = s;
        mx = fmaxf(mx, s);
      }
    mx = fmaxf(mx, __shfl_xor(mx, 16));
    mx = fmaxf(mx, __shfl_xor(mx, 32));
    float sum = 0.f;
    #pragma unroll
    for (int tk = 0; tk < 2; tk++)
      #pragma unroll
      for (int r = 0; r < 4; r++){
        e[tk][r] = __expf(e[tk][r] - mx);
        sum += e[tk][r];
      }
    sum += __shfl_xor(sum, 16);
    sum += __shfl_xor(sum, 32);
    float rinv = 1.f / sum;
    #pragma unroll
    for (int tk = 0; tk < 2; tk++){
      pkk[tq][tk][0] = pkrtz(e[tk][0] * rinv, e[tk][1] * rinv);
      pkk[tq][tk][1] = pkrtz(e[tk][2] * rinv, e[tk][3] * rinv);
    }
  }

  h8_t aP[2];
  #pragma unroll
  for (int tq = 0; tq < 2; tq++){
    union { u32 w[4]; h8_t h; } uu;
    #pragma unroll
    for (int w = 0; w < 4; w++){
      int srcLane = ((kg & 1) * 2 + (w >> 1)) * 16 + m;
      u32 v0 = __shfl(pkk[tq][0][w & 1], srcLane);
      u32 v1 = __shfl(pkk[tq][1][w & 1], srcLane);
      uu.w[w] = (kg >= 2) ? v1 : v0;
    }
    aP[tq] = uu.h;
  }

  f4_t o_[2][2];
  #pragma unroll
  for (int tq = 0; tq < 2; tq++)
    #pragma unroll
    for (int td = 0; td < 2; td++){
      o_[tq][td] = (f4_t)0.f;
      o_[tq][td] = __builtin_amdgcn_mfma_f32_16x16x32_f16(aP[tq], bV[td], o_[tq][td], 0, 0, 0);
    }

  #pragma unroll
  for (int tq = 0; tq < 2; tq++)
    #pragma unroll
    for (int td = 0; td < 2; td++){
      int i0 = tq * 16 + kg * 4, d = td * 16 + m;
      union { u32 w[2]; ushort4 v; } pk2;
      pk2.w[0] = pkrtz(o_[tq][td][0], o_[tq][td][1]);
      pk2.w[1] = pkrtz(o_[tq][td][2], o_[tq][td][3]);
      *(ushort4*)&smem[18432 + seq * 1152 + d * 36 + i0] = pk2.v;
    }
  __syncthreads();

  #pragma unroll
  for (int rep = 0; rep < 2; rep++){
    int idx2 = rep * 512 + tid;
    if (AXIS != 2){
      int i2 = idx2 & 31, f = idx2 >> 5;
      us8_t ov;
      #pragma unroll
      for (int g = 0; g < 8; g++) ov[g] = smem[18432 + g * 1152 + f * 36 + i2];
      size_t go = base + (size_t)f * THW_ + (size_t)i2 * SS;
      *(us8_t*)(ctx + go) = ov;
    } else {
      int i8 = (idx2 & 3) * 8, g2 = (idx2 >> 2) & 7, f = idx2 >> 5;
      int rb = 18432 + g2 * 1152 + f * 36 + i8;
      ushort4 lo = *(const ushort4*)&smem[rb];
      ushort4 hi = *(const ushort4*)&smem[rb + 4];
      us8_t ov;
      ov[0] = lo.x; ov[1] = lo.y; ov[2] = lo.z; ov[3] = lo.w;
      ov[4] = hi.x; ov[5] = hi.y; ov[6] = hi.z; ov[7] = hi.w;
      size_t go = base + (size_t)f * THW_ + (size_t)g2 * GS + i8;
      *(us8_t*)(ctx + go) = ov;
    }
  }
}

// ---------------- fused attention dispatcher: sequential axes ----------------
__global__ __launch_bounds__(512) void k_attn_all(
    const __half* __restrict__ qg_, const __half* __restrict__ kg_,
    const __half* __restrict__ vg_,
    __half* __restrict__ ctx_t, __half* __restrict__ ctx_h, __half* __restrict__ ctx_w,
    const float* __restrict__ cosT, const float* __restrict__ sinT)
{
  __shared__ __align__(16) unsigned short smem[27648];   // 55.3 KB
  const unsigned short* qp = (const unsigned short*)qg_;
  const unsigned short* kp = (const unsigned short*)kg_;
  const unsigned short* vp = (const unsigned short*)vg_;
  int ax = blockIdx.x >> 11;
  int id = blockIdx.x & 2047;
  int ggrp = (id >> 3) & 3;
  int rest = ((id >> 5) << 3) | (id & 7);
  int outer = rest & 31, head = (rest >> 5) & 7, b = rest >> 8;
  if (ax == 0)      attn_body<0>(ggrp, outer, head, b, smem, qp, kp, vp, (unsigned short*)ctx_t, cosT, sinT);
  else if (ax == 1) attn_body<1>(ggrp, outer, head, b, smem, qp, kp, vp, (unsigned short*)ctx_h, cosT, sinT);
  else              attn_body<2>(ggrp, outer, head, b, smem, qp, kp, vp, (unsigned short*)ctx_w, cosT, sinT);
}

extern "C" void kernel_launch(void* const* d_in, const int* in_sizes, int n_in,
                              void* d_out, int out_size, void* d_ws, size_t ws_size,
                              hipStream_t stream)
{
  (void)in_sizes; (void)n_in; (void)out_size; (void)ws_size;
  const float* x       = (const float*)d_in[0];
  const float* w_qkv   = (const float*)d_in[1];
  const float* wk_bank = (const float*)d_in[2];
  const float* wv_bank = (const float*)d_in[3];
  const float* pre_w   = (const float*)d_in[4];
  const float* pre_b   = (const float*)d_in[5];
  const float* cw      = (const float*)d_in[6];
  const float* cb      = (const float*)d_in[7];
  const float* gate_w  = (const float*)d_in[8];
  const float* gate_b  = (const float*)d_in[9];
  const float* proj_w  = (const float*)d_in[10];

  const size_t SZ = (size_t)B_ * C_ * THW_;           // 16,777,216 elems
  __half* hb = (__half*)d_ws;                         // 32MB slots
  unsigned short* xT  = (unsigned short*)(hb + 0 * SZ);  // bf16, alive to gate
  __half* qH   = hb + 1 * SZ;                         // q
  __half* kH   = hb + 2 * SZ;                         // k -> ctx_t
  __half* vH   = hb + 3 * SZ;                         // v -> ctx_h
  __half* koH  = hb + 4 * SZ;                         // k_out -> yT(bf16)
  __half* voH  = hb + 5 * SZ;                         // v_out (stays valid)
  __half* ctxtH = kH;
  __half* ctxhH = vH;
  __half* ctxwH = (__half*)d_out;                     // ctx_w in d_out (dead until proj)
  unsigned short* yT = (unsigned short*)koH;          // over dead k_out
  float* sm    = (float*)(hb + 6 * SZ);               // smalls
  float* qg    = sm;                                  // 16384
  float* hbuf  = qg + 16384;                          // 16384
  float* alpha = hbuf + 16384;                        // 192
  float* cosT  = alpha + 192;                         // 512
  float* sinT  = cosT + 512;                          // 512
  unsigned short* wB = (unsigned short*)(sinT + 512); // 1792*256 bf16 (896 KB)
  unsigned short* wBq = wB;                           // [768][256]
  unsigned short* wBg = wB + 768 * 256;               // [768][256]
  unsigned short* wBp = wB + 1536 * 256;              // [256][256]

  k_rope_table<<<1, 512, 0, stream>>>(cosT, sinT);
  k_wcvt<<<1792, 256, 0, stream>>>(w_qkv, gate_w, proj_w, wB);
  k_transpose_cvt<float><<<dim3(512, 4, 2), 256, 0, stream>>>(x, xT);

  hipMemsetAsync(qg, 0, 16384 * sizeof(float), stream);
  k_mfma_qkv<<<3072, 256, 0, stream>>>(wBq, xT, qH, kH, vH, qg);

  k_mix_pre<<<64, 256, 0, stream>>>(pre_w, pre_b, qg, hbuf);
  k_mix_alpha<<<64, 256, 0, stream>>>(cw, cb, hbuf, alpha);

  k_conv_mix2<<<16384, 256, 0, stream>>>(kH, vH, wk_bank, wv_bank, alpha, koH, voH);

  k_attn_all<<<6144, 512, 0, stream>>>(qH, koH, voH, ctxtH, ctxhH, ctxwH, cosT, sinT);

  k_mfma_gate2<<<4096, 256, 0, stream>>>(wBg, xT, gate_b,
                                         ctxtH, ctxhH, ctxwH, yT); // yT over dead k_out
  k_mfma_proj<<<1024, 256, 0, stream>>>(wBp, yT, (float*)d_out);
}

// Round 19
// 340.888 us; speedup vs baseline: 1.0716x; 1.0038x over previous
//
#include <hip/hip_runtime.h>
#include <hip/hip_fp16.h>
#include <math.h>

#define B_   2
#define C_   256
#define T_   32
#define HW_  1024
#define THW_ 32768

using u32 = unsigned int;
typedef __attribute__((ext_vector_type(8))) short bf8_t;   // 8 bf16 in 4 VGPRs
typedef __attribute__((ext_vector_type(8))) unsigned short us8_t;
typedef __attribute__((ext_vector_type(8))) _Float16 h8_t; // 8 f16 in 4 VGPRs
typedef __attribute__((ext_vector_type(2))) __fp16 fp16v2; // builtin cvt_pkrtz return type
typedef __attribute__((ext_vector_type(4))) float f4_t;

static __device__ __forceinline__ unsigned short f2bf(float x){
  u32 u = __float_as_uint(x);
  u32 r = (u + 0x7FFF + ((u >> 16) & 1)) >> 16;   // RNE
  return (unsigned short)r;
}
static __device__ __forceinline__ float h2f_u(unsigned short u){
  union { __half h; unsigned short us; } cv; cv.us = u; return __half2float(cv.h);
}
static __device__ __forceinline__ unsigned short f2h_u(float f){
  union { __half h; unsigned short us; } cv; cv.h = __float2half(f); return cv.us;
}
static __device__ __forceinline__ u32 pkrtz(float a, float b){
  union { fp16v2 h; u32 w; } cv; cv.h = __builtin_amdgcn_cvt_pkrtz(a, b); return cv.w;
}
static __device__ __forceinline__ float ldf(const float* p){ return *p; }
static __device__ __forceinline__ float ldf(const __half* p){ return __half2float(*p); }

// ---------------- weight cvt (+ rope table in blocks 0-1) ----------------
__global__ void k_wcvt(const float* __restrict__ w_qkv, const float* __restrict__ gate_w,
                       const float* __restrict__ proj_w, unsigned short* __restrict__ out,
                       float* __restrict__ cosT, float* __restrict__ sinT){
  int row = blockIdx.x, c = threadIdx.x;
  const float* src = (row < 768) ? w_qkv + (size_t)row * 256
                   : (row < 1536) ? gate_w + (size_t)(row - 768) * 256
                                  : proj_w + (size_t)(row - 1536) * 256;
  out[(size_t)row * 256 + c] = f2bf(src[c]);
  if (row < 2){
    int tid2 = row * 256 + c;         // 0..511 = i*16+u
    int i = tid2 >> 4, u = tid2 & 15;
    float invf = powf(10000.f, -(2.f * (float)u) / 32.f);
    float s, cc;
    sincosf((float)i * invf, &s, &cc);
    cosT[tid2] = cc;
    sinT[tid2] = s;
  }
}

// ---------------- transpose+cvt: [b][256][THW] f32 -> bf16 [b][THW][256] ----------------
template<typename InT>
__global__ __launch_bounds__(256) void k_transpose_cvt(
    const InT* __restrict__ in, unsigned short* __restrict__ outT)
{
  __shared__ float tile[64][65];
  int s0 = blockIdx.x * 64;     // 512
  int c0 = blockIdx.y * 64;     // 4
  int b  = blockIdx.z;
  int tid = threadIdx.x;
  for (int idx = tid; idx < 4096; idx += 256){
    int c = idx >> 6, s = idx & 63;
    tile[c][s] = ldf(&in[((size_t)(b * C_ + c0 + c)) * THW_ + s0 + s]);
  }
  __syncthreads();
  for (int idx = tid; idx < 4096; idx += 256){
    int s = idx >> 6, c = idx & 63;
    outT[((size_t)b * THW_ + s0 + s) * 256 + c0 + c] = f2bf(tile[c][s]);
  }
}

// ---------------- MFMA GEMM core (bf16 A bank): 128xBN tile, K=256 ----------------
template<int BN>
static __device__ __forceinline__ void gemm_core_b(
    const unsigned short* __restrict__ A, int o0,
    const unsigned short* __restrict__ BT,   // pre-offset: + (b*THW + s0)*256
    unsigned short* As, unsigned short* Bs, f4_t acc[4][BN / 32])
{
  const int tid = threadIdx.x;
  const int lane = tid & 63, wv = tid >> 6;
  const int wm = wv >> 1, wn = wv & 1;
  const int m = lane & 15, kg = lane >> 4;
  const int arow = tid >> 1, aseg = (tid & 1) * 64;     // A: 128 rows, 2 thr/row, 64B each
  const int brow = (BN == 128) ? (tid >> 1) : (tid >> 2);
  const int bseg = (BN == 128) ? (tid & 1) * 64 : (tid & 3) * 32;
  for (int ks = 0; ks < 4; ks++){
    __syncthreads();                                    // protect prior reads
    {
      const unsigned short* ga = A + (size_t)(o0 + arow) * 256 + ks * 64 + aseg / 2;
      #pragma unroll
      for (int q2 = 0; q2 < 4; q2++){
        us8_t v = *(const us8_t*)(ga + q2 * 8);
        *(us8_t*)((char*)As + arow * 128 + ((aseg + q2 * 16) ^ ((arow & 7) << 4))) = v;
      }
      const unsigned short* gb = BT + (size_t)brow * 256 + ks * 64 + bseg / 2;
      #pragma unroll
      for (int q2 = 0; q2 < (BN == 128 ? 4 : 2); q2++){
        us8_t v = *(const us8_t*)(gb + q2 * 8);
        *(us8_t*)((char*)Bs + brow * 128 + ((bseg + q2 * 16) ^ ((brow & 7) << 4))) = v;
      }
    }
    __syncthreads();
    #pragma unroll
    for (int kk = 0; kk < 2; kk++){
      bf8_t af[4], bfr[BN / 32];
      #pragma unroll
      for (int mi = 0; mi < 4; mi++){
        int row = wm * 64 + mi * 16 + m;
        af[mi] = *(const bf8_t*)((const char*)As + row * 128 + ((kk * 64 + kg * 16) ^ ((row & 7) << 4)));
      }
      #pragma unroll
      for (int ni = 0; ni < BN / 32; ni++){
        int row = wn * (BN / 2) + ni * 16 + m;
        bfr[ni] = *(const bf8_t*)((const char*)Bs + row * 128 + ((kk * 64 + kg * 16) ^ ((row & 7) << 4)));
      }
      #pragma unroll
      for (int mi = 0; mi < 4; mi++)
        #pragma unroll
        for (int ni = 0; ni < BN / 32; ni++)
          acc[mi][ni] = __builtin_amdgcn_mfma_f32_16x16x32_bf16(af[mi], bfr[ni], acc[mi][ni], 0, 0, 0);
    }
  }
}

// ---------------- qkv GEMM: Wq(bf16)[768][256] @ x -> q,k,v (f16); fused q-mean ----------
__global__ __launch_bounds__(256) void k_mfma_qkv(
    const unsigned short* __restrict__ Wb, const unsigned short* __restrict__ xT,
    __half* __restrict__ q, __half* __restrict__ k, __half* __restrict__ v,
    float* __restrict__ qg)
{
  __shared__ unsigned short As[8192], Bs[8192];
  int swz = (blockIdx.x & 7) * 384 + (blockIdx.x >> 3);   // 3072 blocks, %8==0
  const int bo = swz % 6;  swz /= 6;
  const int s0 = (swz & 255) * 128;
  const int b  = swz >> 8;
  f4_t acc[4][4];
  #pragma unroll
  for (int mi = 0; mi < 4; mi++)
    #pragma unroll
    for (int ni = 0; ni < 4; ni++) acc[mi][ni] = (f4_t)0.f;
  gemm_core_b<128>(Wb, bo * 128, xT + ((size_t)b * THW_ + s0) * 256, As, Bs, acc);
  __half* outp = (bo < 2) ? q : (bo < 4) ? k : v;
  const int ro = (bo & 1) * 128;
  const int lane = threadIdx.x & 63, wv = threadIdx.x >> 6;
  const int wm = wv >> 1, wn = wv & 1;
  size_t obase = (size_t)(b * C_) * THW_;
  #pragma unroll
  for (int mi = 0; mi < 4; mi++)
    #pragma unroll
    for (int ni = 0; ni < 4; ni++)
      #pragma unroll
      for (int r = 0; r < 4; r++){
        int o = ro + wm * 64 + mi * 16 + (lane >> 4) * 4 + r;
        int s = s0 + wn * 64 + ni * 16 + (lane & 15);
        outp[obase + (size_t)o * THW_ + s] = __float2half(acc[mi][ni][r]);
      }
  // fused mean over (h,w) for q slices: block's 128 s-cols lie within one t.
  if (bo < 2){
    const int t = s0 >> 10;
    #pragma unroll
    for (int mi = 0; mi < 4; mi++)
      #pragma unroll
      for (int r = 0; r < 4; r++){
        float sum = acc[mi][0][r] + acc[mi][1][r] + acc[mi][2][r] + acc[mi][3][r];
        sum += __shfl_xor(sum, 1);
        sum += __shfl_xor(sum, 2);
        sum += __shfl_xor(sum, 4);
        sum += __shfl_xor(sum, 8);
        if ((lane & 15) == 0){
          int o = ro + wm * 64 + mi * 16 + (lane >> 4) * 4 + r;
          atomicAdd(&qg[((size_t)(b * C_ + o)) * T_ + t], sum * (1.f / 1024.f));
        }
      }
  }
}

// ---------------- gate GEMM + sigmoid + combine, 3 slices, yT direct; LDS-staged ctx --------
__global__ __launch_bounds__(256) void k_mfma_gate2(
    const unsigned short* __restrict__ Wb,   // bf16 gate bank [768][256]
    const unsigned short* __restrict__ xT,
    const float* __restrict__ gb,
    const __half* __restrict__ ctx_t, const __half* __restrict__ ctx_h,
    const __half* __restrict__ ctx_w,
    unsigned short* __restrict__ yT)         // bf16 [b][THW][256]
{
  __shared__ unsigned short As3[13056];      // main loop: 3x4096 W tiles; epilogue: 3x[64][68] ctx
  __shared__ unsigned short Bs[4096];
  int swz = (blockIdx.x & 7) * 512 + (blockIdx.x >> 3);   // 4096 blocks
  const int bo = swz & 3;  swz >>= 2;
  const int s0 = (swz & 511) * 64;
  const int b  = swz >> 9;
  const int tid = threadIdx.x;
  const int lane = tid & 63, wv = tid >> 6;
  const int wm = wv >> 1, wn = wv & 1;
  const int m = lane & 15, kg = lane >> 4;
  const unsigned short* xbase = xT + ((size_t)b * THW_ + s0) * 256;
  const size_t obase = (size_t)(b * C_) * THW_;

  f4_t acc[3][2][2];
  #pragma unroll
  for (int sl = 0; sl < 3; sl++)
    #pragma unroll
    for (int mi = 0; mi < 2; mi++)
      #pragma unroll
      for (int ni = 0; ni < 2; ni++) acc[sl][mi][ni] = (f4_t)0.f;

  for (int ks = 0; ks < 4; ks++){
    __syncthreads();
    #pragma unroll
    for (int rep = 0; rep < 2; rep++){
      int idx = rep * 256 + tid;              // 0..511
      int row = idx >> 3, seg = idx & 7;
      us8_t v = *(const us8_t*)(xbase + (size_t)row * 256 + ks * 64 + seg * 8);
      *(us8_t*)((char*)Bs + row * 128 + ((seg * 16) ^ ((row & 7) << 4))) = v;
    }
    #pragma unroll
    for (int sl = 0; sl < 3; sl++){
      #pragma unroll
      for (int rep = 0; rep < 2; rep++){
        int idx = rep * 256 + tid;
        int row = idx >> 3, seg = idx & 7;
        us8_t v = *(const us8_t*)(Wb + (size_t)(sl * 256 + bo * 64 + row) * 256 + ks * 64 + seg * 8);
        *(us8_t*)((char*)As3 + sl * 8192 + row * 128 + ((seg * 16) ^ ((row & 7) << 4))) = v;
      }
    }
    __syncthreads();
    #pragma unroll
    for (int kk = 0; kk < 2; kk++){
      bf8_t bfr[2], af[3][2];
      #pragma unroll
      for (int ni = 0; ni < 2; ni++){
        int row = wn * 32 + ni * 16 + m;
        bfr[ni] = *(const bf8_t*)((const char*)Bs + row * 128 + ((kk * 64 + kg * 16) ^ ((row & 7) << 4)));
      }
      #pragma unroll
      for (int sl = 0; sl < 3; sl++)
        #pragma unroll
        for (int mi = 0; mi < 2; mi++){
          int row = wm * 32 + mi * 16 + m;
          af[sl][mi] = *(const bf8_t*)((const char*)As3 + sl * 8192 + row * 128 + ((kk * 64 + kg * 16) ^ ((row & 7) << 4)));
        }
      #pragma unroll
      for (int sl = 0; sl < 3; sl++)
        #pragma unroll
        for (int mi = 0; mi < 2; mi++)
          #pragma unroll
          for (int ni = 0; ni < 2; ni++)
            acc[sl][mi][ni] = __builtin_amdgcn_mfma_f32_16x16x32_bf16(af[sl][mi], bfr[ni], acc[sl][mi][ni], 0, 0, 0);
    }
  }

  // ---- stage ctx tiles into LDS: 3 slices x [64 o][68 stride] f16, us8 global loads ----
  __syncthreads();                            // MFMA reads of As3 done
  #pragma unroll
  for (int rep = 0; rep < 6; rep++){
    int job = rep * 256 + tid;                // 0..1535 = sl(3) x row(64) x c8(8)
    int sl = job >> 9;
    int row = (job >> 3) & 63;
    int c8 = job & 7;
    const __half* cp = (sl == 0) ? ctx_t : (sl == 1) ? ctx_h : ctx_w;
    us8_t v = *(const us8_t*)((const unsigned short*)cp + obase
                            + (size_t)(bo * 64 + row) * THW_ + s0 + c8 * 8);
    unsigned short* dst = &As3[sl * 4352 + row * 68 + c8 * 8];
    ushort4 lo, hi;
    lo.x = v[0]; lo.y = v[1]; lo.z = v[2]; lo.w = v[3];
    hi.x = v[4]; hi.y = v[5]; hi.z = v[6]; hi.w = v[7];
    *(ushort4*)dst = lo;
    *(ushort4*)(dst + 4) = hi;
  }
  __syncthreads();

  f4_t yacc[2][2];
  #pragma unroll
  for (int mi = 0; mi < 2; mi++)
    #pragma unroll
    for (int ni = 0; ni < 2; ni++) yacc[mi][ni] = (f4_t)0.f;
  #pragma unroll
  for (int sl = 0; sl < 3; sl++){
    #pragma unroll
    for (int mi = 0; mi < 2; mi++)
      #pragma unroll
      for (int ni = 0; ni < 2; ni++)
        #pragma unroll
        for (int r = 0; r < 4; r++){
          int ol = wm * 32 + mi * 16 + kg * 4 + r;
          int sli = wn * 32 + ni * 16 + m;
          float lg = acc[sl][mi][ni][r] + gb[sl * 256 + bo * 64 + ol];
          float g = __builtin_amdgcn_rcpf(1.f + __expf(-lg));
          yacc[mi][ni][r] += g * h2f_u(As3[sl * 4352 + ol * 68 + sli]);
        }
  }

  __syncthreads();                            // ctx reads done before yT tile overwrites
  unsigned short* tile = As3;                 // [64 s][72] bf16
  #pragma unroll
  for (int mi = 0; mi < 2; mi++)
    #pragma unroll
    for (int ni = 0; ni < 2; ni++){
      int ol = wm * 32 + mi * 16 + kg * 4;
      int sl2 = wn * 32 + ni * 16 + m;
      ushort4 w4;
      w4.x = f2bf(yacc[mi][ni][0]);
      w4.y = f2bf(yacc[mi][ni][1]);
      w4.z = f2bf(yacc[mi][ni][2]);
      w4.w = f2bf(yacc[mi][ni][3]);
      *(ushort4*)&tile[sl2 * 72 + ol] = w4;
    }
  __syncthreads();
  {
    int sr = tid >> 2, oc = (tid & 3) * 16;
    us8_t v0 = *(const us8_t*)&tile[sr * 72 + oc];
    us8_t v1 = *(const us8_t*)&tile[sr * 72 + oc + 8];
    unsigned short* dst = yT + ((size_t)b * THW_ + s0 + sr) * 256 + bo * 64 + oc;
    *(us8_t*)dst = v0;
    *(us8_t*)(dst + 8) = v1;
  }
}

// ---------------- proj GEMM -> d_out (f32); XCD-swizzled ----------------
__global__ __launch_bounds__(256) void k_mfma_proj(
    const unsigned short* __restrict__ Wb, const unsigned short* __restrict__ yT,
    float* __restrict__ out)
{
  __shared__ unsigned short As[8192], Bs[8192];
  int swz = (blockIdx.x & 7) * 128 + (blockIdx.x >> 3);   // 1024 blocks
  const int bo = swz & 1;  swz >>= 1;
  const int s0 = (swz & 255) * 128;
  const int b  = swz >> 8;
  f4_t acc[4][4];
  #pragma unroll
  for (int mi = 0; mi < 4; mi++)
    #pragma unroll
    for (int ni = 0; ni < 4; ni++) acc[mi][ni] = (f4_t)0.f;
  gemm_core_b<128>(Wb, bo * 128, yT + ((size_t)b * THW_ + s0) * 256, As, Bs, acc);
  const int lane = threadIdx.x & 63, wv = threadIdx.x >> 6;
  const int wm = wv >> 1, wn = wv & 1;
  size_t obase = (size_t)(b * C_) * THW_;
  #pragma unroll
  for (int mi = 0; mi < 4; mi++)
    #pragma unroll
    for (int ni = 0; ni < 4; ni++)
      #pragma unroll
      for (int r = 0; r < 4; r++){
        int o = bo * 128 + wm * 64 + mi * 16 + (lane >> 4) * 4 + r;
        int s = s0 + wn * 64 + ni * 16 + (lane & 15);
        out[obase + (size_t)o * THW_ + s] = acc[mi][ni][r];
      }
}

// ---------------- fused mix: h = gelu(preW qg + preB) at t-2..t, logits+softmax -> alpha ----
__global__ __launch_bounds__(256) void k_mix_fused(
    const float* __restrict__ preW, const float* __restrict__ preB,
    const float* __restrict__ qg,
    const float* __restrict__ cw, const float* __restrict__ cb,
    float* __restrict__ alpha)
{
  int b = blockIdx.x >> 5, t = blockIdx.x & 31;
  int c = threadIdx.x;
  __shared__ float qgl[3][256];
  #pragma unroll
  for (int j = 0; j < 3; j++){
    int tt = t - 2 + j;
    qgl[j][c] = (tt >= 0) ? qg[((size_t)(b * C_ + c)) * T_ + tt] : 0.f;
  }
  __syncthreads();
  float a0 = 0.f, a1 = 0.f, a2 = 0.f;
  const float* wr = preW + (size_t)c * C_;
  for (int c2 = 0; c2 < C_; c2++){
    float w = wr[c2];
    a0 = fmaf(w, qgl[0][c2], a0);
    a1 = fmaf(w, qgl[1][c2], a1);
    a2 = fmaf(w, qgl[2][c2], a2);
  }
  float pb = preB[c];
  float hv[3];
  hv[0] = (t - 2 >= 0) ? 0.5f * (a0 + pb) * (1.f + erff((a0 + pb) * 0.70710678118f)) : 0.f;
  hv[1] = (t - 1 >= 0) ? 0.5f * (a1 + pb) * (1.f + erff((a1 + pb) * 0.70710678118f)) : 0.f;
  hv[2] = 0.5f * (a2 + pb) * (1.f + erff((a2 + pb) * 0.70710678118f));

  float p[3];
  #pragma unroll
  for (int m = 0; m < 3; m++){
    const float* w = cw + ((size_t)m * C_ + c) * 3;
    p[m] = w[0] * hv[0] + w[1] * hv[1] + w[2] * hv[2];
  }
  #pragma unroll
  for (int m = 0; m < 3; m++){
    #pragma unroll
    for (int off = 32; off; off >>= 1) p[m] += __shfl_down(p[m], off);
  }
  __shared__ float red[3][4];
  int lane = threadIdx.x & 63, w = threadIdx.x >> 6;
  if (lane == 0){ red[0][w] = p[0]; red[1][w] = p[1]; red[2][w] = p[2]; }
  __syncthreads();
  if (threadIdx.x == 0){
    float lg[3];
    #pragma unroll
    for (int m = 0; m < 3; m++) lg[m] = red[m][0] + red[m][1] + red[m][2] + red[m][3] + cb[m];
    float mx = fmaxf(lg[0], fmaxf(lg[1], lg[2]));
    float e0 = __expf(lg[0] - mx), e1 = __expf(lg[1] - mx), e2 = __expf(lg[2] - mx);
    float r = 1.f / (e0 + e1 + e2);
    alpha[((size_t)(b * 3 + 0)) * T_ + t] = e0 * r;
    alpha[((size_t)(b * 3 + 1)) * T_ + t] = e1 * r;
    alpha[((size_t)(b * 3 + 2)) * T_ + t] = e2 * r;
  }
}

// ---------------- alpha-mixed causal depthwise conv 3x3x3, k AND v fused in one block --------
__global__ __launch_bounds__(256) void k_conv_mix2(
    const __half* __restrict__ kin, const __half* __restrict__ vin,
    const float* __restrict__ wkb, const float* __restrict__ wvb,
    const float* __restrict__ alpha,
    __half* __restrict__ kout, __half* __restrict__ vout)
{
  int bi = blockIdx.x;
  int c = bi & 255, t = (bi >> 8) & 31, b = bi >> 13;
  __shared__ float sK[3 * 34 * 35];    // 3570 f32
  __shared__ float sV[3 * 34 * 35];
  __shared__ float wmix[2][27];
  const int tid = threadIdx.x;
  if (tid < 54){
    int which = (tid >= 27) ? 1 : 0;
    int tap = tid - 27 * which;
    const float* bank = which ? wvb : wkb;
    float sum = 0.f;
    #pragma unroll
    for (int m = 0; m < 3; m++)
      sum += alpha[((size_t)(b * 3 + m)) * T_ + t] * bank[((size_t)m * C_ + c) * 27 + tap];
    wmix[which][tap] = sum;
  }
  const size_t cbase = ((size_t)(b * C_ + c)) * T_;

  #pragma unroll
  for (int rep = 0; rep < 2; rep++){
    int job = rep * 256 + tid;
    if (job < 408){
      int half = job & 1;
      int rr = job >> 1;
      int which = (rr >= 102) ? 1 : 0;
      int r = rr - 102 * which;
      int tp = (r >= 68) ? 2 : (r >= 34) ? 1 : 0;
      int yy = r - 34 * tp;
      int tin = t - 2 + tp;
      float* dst = (which ? sV : sK) + tp * 1190 + yy * 35 + 1 + half * 16;
      bool ok = (tin >= 0) && (yy >= 1) && (yy <= 32);
      if (ok){
        const unsigned short* src = (const unsigned short*)((which ? vin : kin)
                                  + (cbase + tin) * HW_ + (size_t)(yy - 1) * 32 + half * 16);
        us8_t v0 = *(const us8_t*)src;
        us8_t v1 = *(const us8_t*)(src + 8);
        #pragma unroll
        for (int j = 0; j < 8; j++) dst[j] = h2f_u(v0[j]);
        #pragma unroll
        for (int j = 0; j < 8; j++) dst[j + 8] = h2f_u(v1[j]);
      } else {
        #pragma unroll
        for (int j = 0; j < 16; j++) dst[j] = 0.f;
      }
      if (half == 0) dst[-1] = 0.f;
      else           dst[16] = 0.f;
    }
  }
  __syncthreads();

  const int y = tid >> 3, x0 = (tid & 7) * 4;
  #pragma unroll
  for (int which = 0; which < 2; which++){
    const float* buf = which ? sV : sK;
    const float* wm = wmix[which];
    float a[4] = {0.f, 0.f, 0.f, 0.f};
    #pragma unroll
    for (int dt = 0; dt < 3; dt++){
      #pragma unroll
      for (int dy = 0; dy < 3; dy++){
        const float* row = buf + dt * 1190 + (y + dy) * 35 + x0;
        float w0 = wm[dt * 9 + dy * 3 + 0];
        float w1 = wm[dt * 9 + dy * 3 + 1];
        float w2 = wm[dt * 9 + dy * 3 + 2];
        float c0 = row[0], c1 = row[1], c2 = row[2];
        float c3 = row[3], c4 = row[4], c5 = row[5];
        a[0] = fmaf(w0, c0, fmaf(w1, c1, fmaf(w2, c2, a[0])));
        a[1] = fmaf(w0, c1, fmaf(w1, c2, fmaf(w2, c3, a[1])));
        a[2] = fmaf(w0, c2, fmaf(w1, c3, fmaf(w2, c4, a[2])));
        a[3] = fmaf(w0, c3, fmaf(w1, c4, fmaf(w2, c5, a[3])));
      }
    }
    size_t ob = (cbase + t) * HW_ + (size_t)y * 32 + x0;
    ushort4 o4;
    o4.x = f2h_u(a[0]); o4.y = f2h_u(a[1]);
    o4.z = f2h_u(a[2]); o4.w = f2h_u(a[3]);
    *(ushort4*)((unsigned short*)(which ? vout : kout) + ob) = o4;
  }
}

// ---------------- axial attention body (MFMA), 8 waves/block, one seq per wave ----------------
// r16 layout: Q seq*1152 stride36; K +9216; V 18432 + seq*1152 stride36. 55.3 KB.
// AXIS==2: O fragment (4 consecutive i at fixed d) is global-contiguous -> direct store.
template<int AXIS>
static __device__ __forceinline__ void attn_body(
    int ggrp, int outer, int head, int b, unsigned short* smem,
    const unsigned short* __restrict__ qp, const unsigned short* __restrict__ kp,
    const unsigned short* __restrict__ vp, unsigned short* ctx,
    const float* __restrict__ cosT, const float* __restrict__ sinT)
{
  const int SS = (AXIS == 0) ? HW_ : (AXIS == 1) ? 32 : 1;
  const int GS = (AXIS == 2) ? 32 : 1;
  const int OS = (AXIS == 0) ? 32 : HW_;
  const size_t base = ((size_t)(b * C_ + head * 32)) * THW_ + (size_t)outer * OS + (size_t)(ggrp * 8) * GS;
  const int tid = threadIdx.x;                    // 0..511

  if (AXIS != 2){
    int i = tid & 31, u = tid >> 5;
    size_t glo = base + (size_t)u * THW_ + (size_t)i * SS;
    size_t ghi = glo + (size_t)16 * THW_;
    us8_t ql = *(const us8_t*)(qp + glo), qh = *(const us8_t*)(qp + ghi);
    us8_t kl = *(const us8_t*)(kp + glo), kh = *(const us8_t*)(kp + ghi);
    float cv = cosT[i * 16 + u], sv = sinT[i * 16 + u];
    #pragma unroll
    for (int g = 0; g < 8; g++){
      int rb = g * 1152 + i * 36 + 2 * u;
      float a = h2f_u(ql[g]), b2 = h2f_u(qh[g]);
      *(u32*)&smem[rb] = pkrtz(a * cv - b2 * sv, fmaf(b2, cv, a * sv));
      a = h2f_u(kl[g]); b2 = h2f_u(kh[g]);
      *(u32*)&smem[9216 + rb] = pkrtz(a * cv - b2 * sv, fmaf(b2, cv, a * sv));
    }
  } else {
    int i8 = (tid & 3) * 8, g = (tid >> 2) & 7, u = tid >> 5;
    size_t glo = base + (size_t)u * THW_ + (size_t)g * GS + i8;
    size_t ghi = glo + (size_t)16 * THW_;
    us8_t ql = *(const us8_t*)(qp + glo), qh = *(const us8_t*)(qp + ghi);
    us8_t kl = *(const us8_t*)(kp + glo), kh = *(const us8_t*)(kp + ghi);
    #pragma unroll
    for (int p2 = 0; p2 < 8; p2++){
      int i = i8 + p2;
      int rb = g * 1152 + i * 36 + 2 * u;
      float cv = cosT[i * 16 + u], sv = sinT[i * 16 + u];
      float a = h2f_u(ql[p2]), b2 = h2f_u(qh[p2]);
      *(u32*)&smem[rb] = pkrtz(a * cv - b2 * sv, fmaf(b2, cv, a * sv));
      a = h2f_u(kl[p2]); b2 = h2f_u(kh[p2]);
      *(u32*)&smem[9216 + rb] = pkrtz(a * cv - b2 * sv, fmaf(b2, cv, a * sv));
    }
  }
  #pragma unroll
  for (int rep = 0; rep < 2; rep++){
    int idx2 = rep * 512 + tid;
    if (AXIS != 2){
      int i = idx2 & 31, f = idx2 >> 5;
      size_t go = base + (size_t)f * THW_ + (size_t)i * SS;
      us8_t vv = *(const us8_t*)(vp + go);
      #pragma unroll
      for (int g = 0; g < 8; g++) smem[18432 + g * 1152 + f * 36 + i] = vv[g];
    } else {
      int i8 = (idx2 & 3) * 8, g = (idx2 >> 2) & 7, f = idx2 >> 5;
      size_t go = base + (size_t)f * THW_ + (size_t)g * GS + i8;
      us8_t vv = *(const us8_t*)(vp + go);
      int rb = 18432 + g * 1152 + f * 36 + i8;
      ushort4 lo, hi;
      lo.x = vv[0]; lo.y = vv[1]; lo.z = vv[2]; lo.w = vv[3];
      hi.x = vv[4]; hi.y = vv[5]; hi.z = vv[6]; hi.w = vv[7];
      *(ushort4*)&smem[rb] = lo;
      *(ushort4*)&smem[rb + 4] = hi;
    }
  }
  __syncthreads();

  const int lane = tid & 63;
  const int seq = tid >> 6;
  const int m = lane & 15, kg = lane >> 4;

  h8_t aQ[2], bK[2], bV[2];
  #pragma unroll
  for (int t2 = 0; t2 < 2; t2++){
    union { ushort4 u4[2]; h8_t h; } uq, uk, uv;
    int rq = seq * 1152 + (t2 * 16 + m) * 36 + kg * 8;
    uq.u4[0] = *(const ushort4*)&smem[rq];
    uq.u4[1] = *(const ushort4*)&smem[rq + 4];
    uk.u4[0] = *(const ushort4*)&smem[9216 + rq];
    uk.u4[1] = *(const ushort4*)&smem[9216 + rq + 4];
    uv.u4[0] = *(const ushort4*)&smem[18432 + rq];
    uv.u4[1] = *(const ushort4*)&smem[18432 + rq + 4];
    aQ[t2] = uq.h; bK[t2] = uk.h; bV[t2] = uv.h;
  }

  f4_t st[2][2];
  #pragma unroll
  for (int tk = 0; tk < 2; tk++)
    #pragma unroll
    for (int tq = 0; tq < 2; tq++){
      st[tk][tq] = (f4_t)0.f;
      st[tk][tq] = __builtin_amdgcn_mfma_f32_16x16x32_f16(bK[tk], aQ[tq], st[tk][tq], 0, 0, 0);
    }

  u32 pkk[2][2][2];             // [tq][tk][pair]
  #pragma unroll
  for (int tq = 0; tq < 2; tq++){
    const int i = tq * 16 + m;
    float e[2][4];
    float mx = -3.0e38f;
    #pragma unroll
    for (int tk = 0; tk < 2; tk++)
      #pragma unroll
      for (int r = 0; r < 4; r++){
        float s = st[tk][tq][r] * 0.17677669529663687f;
        if (AXIS == 0 && (tk * 16 + kg * 4 + r) > i) s = -1e30f;
        e[tk][r] = s;
        mx = fmaxf(mx, s);
      }
    mx = fmaxf(mx, __shfl_xor(mx, 16));
    mx = fmaxf(mx, __shfl_xor(mx, 32));
    float sum = 0.f;
    #pragma unroll
    for (int tk = 0; tk < 2; tk++)
      #pragma unroll
      for (int r = 0; r < 4; r++){
        e[tk][r] = __expf(e[tk][r] - mx);
        sum += e[tk][r];
      }
    sum += __shfl_xor(sum, 16);
    sum += __shfl_xor(sum, 32);
    float rinv = 1.f / sum;
    #pragma unroll
    for (int tk = 0; tk < 2; tk++){
      pkk[tq][tk][0] = pkrtz(e[tk][0] * rinv, e[tk][1] * rinv);
      pkk[tq][tk][1] = pkrtz(e[tk][2] * rinv, e[tk][3] * rinv);
    }
  }

  h8_t aP[2];
  #pragma unroll
  for (int tq = 0; tq < 2; tq++){
    union { u32 w[4]; h8_t h; } uu;
    #pragma unroll
    for (int w = 0; w < 4; w++){
      int srcLane = ((kg & 1) * 2 + (w >> 1)) * 16 + m;
      u32 v0 = __shfl(pkk[tq][0][w & 1], srcLane);
      u32 v1 = __shfl(pkk[tq][1][w & 1], srcLane);
      uu.w[w] = (kg >= 2) ? v1 : v0;
    }
    aP[tq] = uu.h;
  }

  f4_t o_[2][2];
  #pragma unroll
  for (int tq = 0; tq < 2; tq++)
    #pragma unroll
    for (int td = 0; td < 2; td++){
      o_[tq][td] = (f4_t)0.f;
      o_[tq][td] = __builtin_amdgcn_mfma_f32_16x16x32_f16(aP[tq], bV[td], o_[tq][td], 0, 0, 0);
    }

  if (AXIS == 2){
    // direct O store: thread holds 4 consecutive i at fixed d -> 8B global store
    #pragma unroll
    for (int tq = 0; tq < 2; tq++)
      #pragma unroll
      for (int td = 0; td < 2; td++){
        int i0 = tq * 16 + kg * 4, d = td * 16 + m;
        union { u32 w[2]; ushort4 v; } pk2;
        pk2.w[0] = pkrtz(o_[tq][td][0], o_[tq][td][1]);
        pk2.w[1] = pkrtz(o_[tq][td][2], o_[tq][td][3]);
        *(ushort4*)(ctx + base + (size_t)d * THW_ + seq * 32 + i0) = pk2.v;
      }
    return;
  }

  #pragma unroll
  for (int tq = 0; tq < 2; tq++)
    #pragma unroll
    for (int td = 0; td < 2; td++){
      int i0 = tq * 16 + kg * 4, d = td * 16 + m;
      union { u32 w[2]; ushort4 v; } pk2;
      pk2.w[0] = pkrtz(o_[tq][td][0], o_[tq][td][1]);
      pk2.w[1] = pkrtz(o_[tq][td][2], o_[tq][td][3]);
      *(ushort4*)&smem[18432 + seq * 1152 + d * 36 + i0] = pk2.v;
    }
  __syncthreads();

  #pragma unroll
  for (int rep = 0; rep < 2; rep++){
    int idx2 = rep * 512 + tid;
    int i2 = idx2 & 31, f = idx2 >> 5;
    us8_t ov;
    #pragma unroll
    for (int g = 0; g < 8; g++) ov[g] = smem[18432 + g * 1152 + f * 36 + i2];
    size_t go = base + (size_t)f * THW_ + (size_t)i2 * SS;
    *(us8_t*)(ctx + go) = ov;
  }
}

// ---------------- fused attention dispatcher: sequential axes ----------------
__global__ __launch_bounds__(512) void k_attn_all(
    const __half* __restrict__ qg_, const __half* __restrict__ kg_,
    const __half* __restrict__ vg_,
    __half* __restrict__ ctx_t, __half* __restrict__ ctx_h, __half* __restrict__ ctx_w,
    const float* __restrict__ cosT, const float* __restrict__ sinT)
{
  __shared__ __align__(16) unsigned short smem[27648];   // 55.3 KB
  const unsigned short* qp = (const unsigned short*)qg_;
  const unsigned short* kp = (const unsigned short*)kg_;
  const unsigned short* vp = (const unsigned short*)vg_;
  int ax = blockIdx.x >> 11;
  int id = blockIdx.x & 2047;
  int ggrp = (id >> 3) & 3;
  int rest = ((id >> 5) << 3) | (id & 7);
  int outer = rest & 31, head = (rest >> 5) & 7, b = rest >> 8;
  if (ax == 0)      attn_body<0>(ggrp, outer, head, b, smem, qp, kp, vp, (unsigned short*)ctx_t, cosT, sinT);
  else if (ax == 1) attn_body<1>(ggrp, outer, head, b, smem, qp, kp, vp, (unsigned short*)ctx_h, cosT, sinT);
  else              attn_body<2>(ggrp, outer, head, b, smem, qp, kp, vp, (unsigned short*)ctx_w, cosT, sinT);
}

extern "C" void kernel_launch(void* const* d_in, const int* in_sizes, int n_in,
                              void* d_out, int out_size, void* d_ws, size_t ws_size,
                              hipStream_t stream)
{
  (void)in_sizes; (void)n_in; (void)out_size; (void)ws_size;
  const float* x       = (const float*)d_in[0];
  const float* w_qkv   = (const float*)d_in[1];
  const float* wk_bank = (const float*)d_in[2];
  const float* wv_bank = (const float*)d_in[3];
  const float* pre_w   = (const float*)d_in[4];
  const float* pre_b   = (const float*)d_in[5];
  const float* cw      = (const float*)d_in[6];
  const float* cb      = (const float*)d_in[7];
  const float* gate_w  = (const float*)d_in[8];
  const float* gate_b  = (const float*)d_in[9];
  const float* proj_w  = (const float*)d_in[10];

  const size_t SZ = (size_t)B_ * C_ * THW_;           // 16,777,216 elems
  __half* hb = (__half*)d_ws;                         // 32MB slots
  unsigned short* xT  = (unsigned short*)(hb + 0 * SZ);  // bf16, alive to gate
  __half* qH   = hb + 1 * SZ;                         // q
  __half* kH   = hb + 2 * SZ;                         // k -> ctx_t
  __half* vH   = hb + 3 * SZ;                         // v -> ctx_h
  __half* koH  = hb + 4 * SZ;                         // k_out -> yT(bf16)
  __half* voH  = hb + 5 * SZ;                         // v_out (stays valid)
  __half* ctxtH = kH;
  __half* ctxhH = vH;
  __half* ctxwH = (__half*)d_out;                     // ctx_w in d_out (dead until proj)
  unsigned short* yT = (unsigned short*)koH;          // over dead k_out
  float* sm    = (float*)(hb + 6 * SZ);               // smalls
  float* qg    = sm;                                  // 16384
  float* hbuf  = qg + 16384;                          // 16384 (unused, keeps offsets)
  float* alpha = hbuf + 16384;                        // 192
  float* cosT  = alpha + 192;                         // 512
  float* sinT  = cosT + 512;                          // 512
  unsigned short* wB = (unsigned short*)(sinT + 512); // 1792*256 bf16 (896 KB)
  unsigned short* wBq = wB;                           // [768][256]
  unsigned short* wBg = wB + 768 * 256;               // [768][256]
  unsigned short* wBp = wB + 1536 * 256;              // [256][256]

  k_wcvt<<<1792, 256, 0, stream>>>(w_qkv, gate_w, proj_w, wB, cosT, sinT);
  k_transpose_cvt<float><<<dim3(512, 4, 2), 256, 0, stream>>>(x, xT);

  hipMemsetAsync(qg, 0, 16384 * sizeof(float), stream);
  k_mfma_qkv<<<3072, 256, 0, stream>>>(wBq, xT, qH, kH, vH, qg);

  k_mix_fused<<<64, 256, 0, stream>>>(pre_w, pre_b, qg, cw, cb, alpha);

  k_conv_mix2<<<16384, 256, 0, stream>>>(kH, vH, wk_bank, wv_bank, alpha, koH, voH);

  k_attn_all<<<6144, 512, 0, stream>>>(qH, koH, voH, ctxtH, ctxhH, ctxwH, cosT, sinT);

  k_mfma_gate2<<<4096, 256, 0, stream>>>(wBg, xT, gate_b,
                                         ctxtH, ctxhH, ctxwH, yT); // yT over dead k_out
  k_mfma_proj<<<1024, 256, 0, stream>>>(wBp, yT, (float*)d_out);
}